// Round 1
// baseline (5901.931 us; speedup 1.0000x reference)
//
#include <hip/hip_runtime.h>
#include <hip/hip_bf16.h>
#include <math.h>

#define D 128

__device__ __forceinline__ float gelu_tanh(float x) {
    // jax.nn.gelu approximate=True: 0.5*x*(1+tanh(sqrt(2/pi)*(x+0.044715*x^3)))
    float u = 0.7978845608028654f * (x + 0.044715f * x * x * x);
    return 0.5f * x * (1.0f + tanhf(u));
}

// C[n,128] = gelu(X[n,128] @ W[128,128] + b[128])
__global__ __launch_bounds__(256) void proj_kernel(
    const float* __restrict__ X, const float* __restrict__ W,
    const float* __restrict__ b, float* __restrict__ C, int n)
{
    __shared__ float sX[64][129];   // +1 pad: column reads conflict-free
    const int row0 = blockIdx.x * 64;
    const int tid = threadIdx.x;

    // stage 64x128 A-tile (coalesced float4 global loads)
    #pragma unroll
    for (int p = 0; p < 8; ++p) {
        int flat = (p * 256 + tid) * 4;
        int r = flat >> 7, c = flat & 127;
        int gr = row0 + r;
        if (gr >= n) gr = n - 1;              // clamp; stores are guarded
        const float4 x4 = *reinterpret_cast<const float4*>(X + (size_t)gr * D + c);
        sX[r][c + 0] = x4.x; sX[r][c + 1] = x4.y;
        sX[r][c + 2] = x4.z; sX[r][c + 3] = x4.w;
    }
    __syncthreads();

    const int tr = tid >> 4;     // 0..15 -> rows tr*4..tr*4+3
    const int tc = tid & 15;     // 0..15 -> cols tc*8..tc*8+7
    const int cbase = tc * 8;

    float acc[4][8];
    #pragma unroll
    for (int i = 0; i < 4; ++i)
        #pragma unroll
        for (int j = 0; j < 8; ++j) acc[i][j] = 0.0f;

    const float* Wp = W + cbase;
    #pragma unroll 4
    for (int k = 0; k < D; ++k) {
        float a[4];
        #pragma unroll
        for (int i = 0; i < 4; ++i) a[i] = sX[tr * 4 + i][k];
        float4 w0 = *reinterpret_cast<const float4*>(Wp + k * D);
        float4 w1 = *reinterpret_cast<const float4*>(Wp + k * D + 4);
        float w[8] = {w0.x, w0.y, w0.z, w0.w, w1.x, w1.y, w1.z, w1.w};
        #pragma unroll
        for (int i = 0; i < 4; ++i)
            #pragma unroll
            for (int j = 0; j < 8; ++j)
                acc[i][j] = fmaf(a[i], w[j], acc[i][j]);
    }

    float bb[8];
    #pragma unroll
    for (int j = 0; j < 8; ++j) bb[j] = b[cbase + j];

    #pragma unroll
    for (int i = 0; i < 4; ++i) {
        int gr = row0 + tr * 4 + i;
        if (gr < n) {
            float* Cp = C + (size_t)gr * D + cbase;
            float4 o0, o1;
            o0.x = gelu_tanh(acc[i][0] + bb[0]);
            o0.y = gelu_tanh(acc[i][1] + bb[1]);
            o0.z = gelu_tanh(acc[i][2] + bb[2]);
            o0.w = gelu_tanh(acc[i][3] + bb[3]);
            o1.x = gelu_tanh(acc[i][4] + bb[4]);
            o1.y = gelu_tanh(acc[i][5] + bb[5]);
            o1.z = gelu_tanh(acc[i][6] + bb[6]);
            o1.w = gelu_tanh(acc[i][7] + bb[7]);
            *reinterpret_cast<float4*>(Cp)     = o0;
            *reinterpret_cast<float4*>(Cp + 4) = o1;
        }
    }
}

// One edge per 16 lanes: dot(q[r],k[c]) -> sigmoid -> atomic out[r] += coef*v[c]
__global__ __launch_bounds__(256) void edge_kernel(
    const float* __restrict__ q, const float* __restrict__ k,
    const float* __restrict__ v, const int* __restrict__ rows,
    const int* __restrict__ cols, float* __restrict__ out, int nE)
{
    int t = blockIdx.x * 256 + threadIdx.x;
    int e = t >> 4;
    if (e >= nE) return;
    int l = t & 15;

    int r = rows[e];
    int c = cols[e];

    const float4* qp = reinterpret_cast<const float4*>(q + (size_t)r * D) + l * 2;
    const float4* kp = reinterpret_cast<const float4*>(k + (size_t)c * D) + l * 2;
    float4 a0 = qp[0], a1 = qp[1];
    float4 b0 = kp[0], b1 = kp[1];

    float dot = a0.x * b0.x + a0.y * b0.y + a0.z * b0.z + a0.w * b0.w
              + a1.x * b1.x + a1.y * b1.y + a1.z * b1.z + a1.w * b1.w;
    // reduce across the 16 lanes of this edge (masks < 16 stay in-group)
    dot += __shfl_xor(dot, 1);
    dot += __shfl_xor(dot, 2);
    dot += __shfl_xor(dot, 4);
    dot += __shfl_xor(dot, 8);

    // sigmoid(dot / sqrt(128))
    float coef = 1.0f / (1.0f + expf(-dot * 0.08838834764831845f));

    const float4* vp = reinterpret_cast<const float4*>(v + (size_t)c * D) + l * 2;
    float4 v0 = vp[0], v1 = vp[1];

    float* o = out + (size_t)r * D + l * 8;
    unsafeAtomicAdd(o + 0, coef * v0.x);
    unsafeAtomicAdd(o + 1, coef * v0.y);
    unsafeAtomicAdd(o + 2, coef * v0.z);
    unsafeAtomicAdd(o + 3, coef * v0.w);
    unsafeAtomicAdd(o + 4, coef * v1.x);
    unsafeAtomicAdd(o + 5, coef * v1.y);
    unsafeAtomicAdd(o + 6, coef * v1.z);
    unsafeAtomicAdd(o + 7, coef * v1.w);
}

extern "C" void kernel_launch(void* const* d_in, const int* in_sizes, int n_in,
                              void* d_out, int out_size, void* d_ws, size_t ws_size,
                              hipStream_t stream) {
    const float* query  = (const float*)d_in[0];
    const float* memory = (const float*)d_in[1];
    const float* Wq     = (const float*)d_in[2];
    const float* bq     = (const float*)d_in[3];
    const float* Wk     = (const float*)d_in[4];
    const float* bk     = (const float*)d_in[5];
    const float* Wv     = (const float*)d_in[6];
    const float* bv     = (const float*)d_in[7];
    const int*   erows  = (const int*)d_in[8];
    const int*   ecols  = (const int*)d_in[9];

    const int n  = in_sizes[0] / D;   // 100000
    const int m  = in_sizes[1] / D;   // 100000
    const int nE = in_sizes[8];       // 1600000

    float* q = (float*)d_ws;
    float* k = q + (size_t)n * D;
    float* v = k + (size_t)m * D;
    float* out = (float*)d_out;

    // harness poisons d_out once and never re-poisons between replays
    hipMemsetAsync(out, 0, (size_t)out_size * sizeof(float), stream);

    dim3 blk(256);
    proj_kernel<<<dim3((n + 63) / 64), blk, 0, stream>>>(query,  Wq, bq, q, n);
    proj_kernel<<<dim3((m + 63) / 64), blk, 0, stream>>>(memory, Wk, bk, k, m);
    proj_kernel<<<dim3((m + 63) / 64), blk, 0, stream>>>(memory, Wv, bv, v, m);

    int nBlocks = (int)(((size_t)nE * 16 + 255) / 256);
    edge_kernel<<<dim3(nBlocks), blk, 0, stream>>>(q, k, v, erows, ecols, out, nE);
}

// Round 2
// 783.046 us; speedup vs baseline: 7.5371x; 7.5371x over previous
//
#include <hip/hip_runtime.h>
#include <hip/hip_bf16.h>
#include <math.h>

#define D 128

__device__ __forceinline__ float gelu_tanh(float x) {
    // jax.nn.gelu approximate=True: 0.5*x*(1+tanh(sqrt(2/pi)*(x+0.044715*x^3)))
    float u = 0.7978845608028654f * (x + 0.044715f * x * x * x);
    return 0.5f * x * (1.0f + tanhf(u));
}

// C[n,128] = gelu(X[n,128] @ W[128,128] + b[128])
__global__ __launch_bounds__(256) void proj_kernel(
    const float* __restrict__ X, const float* __restrict__ W,
    const float* __restrict__ b, float* __restrict__ C, int n)
{
    __shared__ float sX[64][129];   // +1 pad: column reads conflict-free
    const int row0 = blockIdx.x * 64;
    const int tid = threadIdx.x;

    #pragma unroll
    for (int p = 0; p < 8; ++p) {
        int flat = (p * 256 + tid) * 4;
        int r = flat >> 7, c = flat & 127;
        int gr = row0 + r;
        if (gr >= n) gr = n - 1;              // clamp; stores are guarded
        const float4 x4 = *reinterpret_cast<const float4*>(X + (size_t)gr * D + c);
        sX[r][c + 0] = x4.x; sX[r][c + 1] = x4.y;
        sX[r][c + 2] = x4.z; sX[r][c + 3] = x4.w;
    }
    __syncthreads();

    const int tr = tid >> 4;
    const int tc = tid & 15;
    const int cbase = tc * 8;

    float acc[4][8];
    #pragma unroll
    for (int i = 0; i < 4; ++i)
        #pragma unroll
        for (int j = 0; j < 8; ++j) acc[i][j] = 0.0f;

    const float* Wp = W + cbase;
    #pragma unroll 4
    for (int k = 0; k < D; ++k) {
        float a[4];
        #pragma unroll
        for (int i = 0; i < 4; ++i) a[i] = sX[tr * 4 + i][k];
        float4 w0 = *reinterpret_cast<const float4*>(Wp + k * D);
        float4 w1 = *reinterpret_cast<const float4*>(Wp + k * D + 4);
        float w[8] = {w0.x, w0.y, w0.z, w0.w, w1.x, w1.y, w1.z, w1.w};
        #pragma unroll
        for (int i = 0; i < 4; ++i)
            #pragma unroll
            for (int j = 0; j < 8; ++j)
                acc[i][j] = fmaf(a[i], w[j], acc[i][j]);
    }

    float bb[8];
    #pragma unroll
    for (int j = 0; j < 8; ++j) bb[j] = b[cbase + j];

    #pragma unroll
    for (int i = 0; i < 4; ++i) {
        int gr = row0 + tr * 4 + i;
        if (gr < n) {
            float* Cp = C + (size_t)gr * D + cbase;
            float4 o0, o1;
            o0.x = gelu_tanh(acc[i][0] + bb[0]);
            o0.y = gelu_tanh(acc[i][1] + bb[1]);
            o0.z = gelu_tanh(acc[i][2] + bb[2]);
            o0.w = gelu_tanh(acc[i][3] + bb[3]);
            o1.x = gelu_tanh(acc[i][4] + bb[4]);
            o1.y = gelu_tanh(acc[i][5] + bb[5]);
            o1.z = gelu_tanh(acc[i][6] + bb[6]);
            o1.w = gelu_tanh(acc[i][7] + bb[7]);
            *reinterpret_cast<float4*>(Cp)     = o0;
            *reinterpret_cast<float4*>(Cp + 4) = o1;
        }
    }
}

// ---- CSR build ----

__global__ __launch_bounds__(256) void hist_kernel(
    const int* __restrict__ rows, int* __restrict__ cnt, int nE)
{
    int e = blockIdx.x * 256 + threadIdx.x;
    if (e < nE) atomicAdd(&cnt[rows[e]], 1);
}

// single-workgroup 3-phase exclusive scan of cnt[0..n-1] -> rowptr[0..n]
__global__ __launch_bounds__(1024) void scan_kernel(
    const int* __restrict__ cnt, int* __restrict__ rowptr, int n)
{
    __shared__ int s[1024];
    const int t = threadIdx.x;
    const int C = (n + 1023) >> 10;
    const int lo = t * C;
    const int hi = min(lo + C, n);

    int sum = 0;
    for (int i = lo; i < hi; ++i) sum += cnt[i];
    s[t] = sum;
    __syncthreads();

    // inclusive Hillis-Steele over 1024 partials
    for (int off = 1; off < 1024; off <<= 1) {
        int val = (t >= off) ? s[t - off] : 0;
        __syncthreads();
        s[t] += val;
        __syncthreads();
    }

    int run = s[t] - sum;   // exclusive prefix of this chunk
    for (int i = lo; i < hi; ++i) {
        rowptr[i] = run;
        run += cnt[i];
    }
    if (t == 1023) rowptr[n] = s[1023];
}

__global__ __launch_bounds__(256) void scatter_kernel(
    const int* __restrict__ rows, const int* __restrict__ cols,
    const int* __restrict__ rowptr, int* __restrict__ cur,
    int* __restrict__ colsorted, int nE)
{
    int e = blockIdx.x * 256 + threadIdx.x;
    if (e >= nE) return;
    int r = rows[e];
    int pos = rowptr[r] + atomicAdd(&cur[r], 1);
    colsorted[pos] = cols[e];
}

// ---- aggregation: one wave per row, 4 edges in flight (16 lanes each) ----
__global__ __launch_bounds__(256) void agg_kernel(
    const float* __restrict__ q, const float* __restrict__ k,
    const float* __restrict__ v, const int* __restrict__ rowptr,
    const int* __restrict__ colsorted, float* __restrict__ out, int n)
{
    const int wave = (blockIdx.x * 256 + threadIdx.x) >> 6;
    if (wave >= n) return;
    const int lane = threadIdx.x & 63;
    const int sub  = lane >> 4;     // edge slot 0..3
    const int l    = lane & 15;     // dim slot: dims l*8 .. l*8+7

    const int r = wave;
    const float4* qp = reinterpret_cast<const float4*>(q + (size_t)r * D + l * 8);
    const float4 q0 = qp[0], q1 = qp[1];

    float acc[8] = {0.f,0.f,0.f,0.f,0.f,0.f,0.f,0.f};
    const int start = rowptr[r], end = rowptr[r + 1];

    for (int i = start + sub; i < end; i += 4) {
        const int c = colsorted[i];
        const float4* kp = reinterpret_cast<const float4*>(k + (size_t)c * D + l * 8);
        const float4 k0 = kp[0], k1 = kp[1];
        float dot = q0.x * k0.x + q0.y * k0.y + q0.z * k0.z + q0.w * k0.w
                  + q1.x * k1.x + q1.y * k1.y + q1.z * k1.z + q1.w * k1.w;
        dot += __shfl_xor(dot, 1);
        dot += __shfl_xor(dot, 2);
        dot += __shfl_xor(dot, 4);
        dot += __shfl_xor(dot, 8);
        const float coef = 1.0f / (1.0f + expf(-dot * 0.08838834764831845f));

        const float4* vp = reinterpret_cast<const float4*>(v + (size_t)c * D + l * 8);
        const float4 v0 = vp[0], v1 = vp[1];
        acc[0] = fmaf(coef, v0.x, acc[0]);
        acc[1] = fmaf(coef, v0.y, acc[1]);
        acc[2] = fmaf(coef, v0.z, acc[2]);
        acc[3] = fmaf(coef, v0.w, acc[3]);
        acc[4] = fmaf(coef, v1.x, acc[4]);
        acc[5] = fmaf(coef, v1.y, acc[5]);
        acc[6] = fmaf(coef, v1.z, acc[6]);
        acc[7] = fmaf(coef, v1.w, acc[7]);
    }

    // combine the 4 edge-slots (lanes l, l+16, l+32, l+48 hold same dims)
    #pragma unroll
    for (int j = 0; j < 8; ++j) {
        acc[j] += __shfl_xor(acc[j], 16);
        acc[j] += __shfl_xor(acc[j], 32);
    }

    if (sub == 0) {
        float* op = out + (size_t)r * D + l * 8;
        float4 o0 = {acc[0], acc[1], acc[2], acc[3]};
        float4 o1 = {acc[4], acc[5], acc[6], acc[7]};
        *reinterpret_cast<float4*>(op)     = o0;
        *reinterpret_cast<float4*>(op + 4) = o1;
    }
}

extern "C" void kernel_launch(void* const* d_in, const int* in_sizes, int n_in,
                              void* d_out, int out_size, void* d_ws, size_t ws_size,
                              hipStream_t stream) {
    const float* query  = (const float*)d_in[0];
    const float* memory = (const float*)d_in[1];
    const float* Wq     = (const float*)d_in[2];
    const float* bq     = (const float*)d_in[3];
    const float* Wk     = (const float*)d_in[4];
    const float* bk     = (const float*)d_in[5];
    const float* Wv     = (const float*)d_in[6];
    const float* bv     = (const float*)d_in[7];
    const int*   erows  = (const int*)d_in[8];
    const int*   ecols  = (const int*)d_in[9];

    const int n  = in_sizes[0] / D;   // 100000
    const int m  = in_sizes[1] / D;   // 100000
    const int nE = in_sizes[8];       // 1600000

    // workspace carve-up (256 B aligned)
    char* base = (char*)d_ws;
    size_t off = 0;
    auto carve = [&](size_t bytes) -> char* {
        char* p = base + off;
        off = (off + bytes + 255) & ~(size_t)255;
        return p;
    };
    float* q         = (float*)carve((size_t)n * D * sizeof(float));
    float* k         = (float*)carve((size_t)m * D * sizeof(float));
    float* v         = (float*)carve((size_t)m * D * sizeof(float));
    int*   rowptr    = (int*)  carve((size_t)(n + 1) * sizeof(int));
    int*   cnt       = (int*)  carve((size_t)(n + 1) * sizeof(int));
    int*   colsorted = (int*)  carve((size_t)nE * sizeof(int));
    float* out       = (float*)d_out;

    dim3 blk(256);

    // CSR build (interleaved with projections; single stream serializes anyway)
    hipMemsetAsync(cnt, 0, (size_t)(n + 1) * sizeof(int), stream);
    hist_kernel<<<dim3((nE + 255) / 256), blk, 0, stream>>>(erows, cnt, nE);
    scan_kernel<<<dim3(1), dim3(1024), 0, stream>>>(cnt, rowptr, n);
    hipMemsetAsync(cnt, 0, (size_t)(n + 1) * sizeof(int), stream);
    scatter_kernel<<<dim3((nE + 255) / 256), blk, 0, stream>>>(erows, ecols, rowptr, cnt, colsorted, nE);

    // projections
    proj_kernel<<<dim3((n + 63) / 64), blk, 0, stream>>>(query,  Wq, bq, q, n);
    proj_kernel<<<dim3((m + 63) / 64), blk, 0, stream>>>(memory, Wk, bk, k, m);
    proj_kernel<<<dim3((m + 63) / 64), blk, 0, stream>>>(memory, Wv, bv, v, m);

    // aggregation: one wave per row -> writes every output element (no memset needed)
    agg_kernel<<<dim3((n * 64 + 255) / 256), blk, 0, stream>>>(q, k, v, rowptr, colsorted, out, n);
}

// Round 3
// 525.208 us; speedup vs baseline: 11.2373x; 1.4909x over previous
//
#include <hip/hip_runtime.h>
#include <hip/hip_bf16.h>
#include <math.h>

#define D 128

typedef float f32x16 __attribute__((ext_vector_type(16)));
typedef short bf16x8 __attribute__((ext_vector_type(8)));

__device__ __forceinline__ float gelu_tanh(float x) {
    // jax.nn.gelu approximate=True
    float u = 0.7978845608028654f * (x + 0.044715f * x * x * x);
    return 0.5f * x * (1.0f + tanhf(u));
}

__device__ __forceinline__ unsigned short f2bf(float f) {
    union { float f; unsigned u; } x; x.f = f;
    unsigned r = x.u + 0x7fff + ((x.u >> 16) & 1);   // RNE
    return (unsigned short)(r >> 16);
}

__device__ __forceinline__ float bflo(unsigned u) { return __uint_as_float(u << 16); }
__device__ __forceinline__ float bfhi(unsigned u) { return __uint_as_float(u & 0xffff0000u); }

// Pre-pack W[128][128] f32 into B-fragment order for mfma_f32_32x32x16_bf16:
// F[((ct*8+kt)*64+l)*8+j] = bf16(W[(kt*16+(l>>5)*8+j)*128 + ct*32+(l&31)])
__global__ __launch_bounds__(256) void prepack_kernel(
    const float* __restrict__ W, unsigned short* __restrict__ F)
{
    int idx = blockIdx.x * 256 + threadIdx.x;
    if (idx >= 32 * 64 * 8) return;
    int j  = idx & 7;
    int l  = (idx >> 3) & 63;
    int kt = (idx >> 9) & 7;
    int ct = idx >> 12;
    int k  = kt * 16 + (l >> 5) * 8 + j;
    int c  = ct * 32 + (l & 31);
    F[idx] = f2bf(W[k * D + c]);
}

// C[i,:] = bf16(gelu(X[i,:] @ W + b)) for one or two W (shared X read).
// Block: 256 thr = 4 waves, 128 rows. Wave w: rows row0+w*32..+31, full 128 cols.
__global__ __launch_bounds__(256) void proj_mfma_kernel(
    const float* __restrict__ X,
    const unsigned short* __restrict__ F1, const float* __restrict__ b1,
    unsigned short* __restrict__ C1,
    const unsigned short* __restrict__ F2, const float* __restrict__ b2,
    unsigned short* __restrict__ C2, int n)
{
    __shared__ __align__(16) unsigned short sX[128][136];  // pad: 272B row stride
    const int tid  = threadIdx.x;
    const int row0 = blockIdx.x * 128;

    // stage 128x128 f32 -> bf16 LDS, coalesced float4 reads
    #pragma unroll
    for (int p = 0; p < 16; ++p) {
        int flat = p * 256 + tid;          // 4096 float4 total
        int r = flat >> 5;
        int c = (flat & 31) * 4;
        int gr = row0 + r; if (gr >= n) gr = n - 1;   // clamp; stores guarded
        float4 x4 = *reinterpret_cast<const float4*>(X + (size_t)gr * D + c);
        unsigned short h0 = f2bf(x4.x), h1 = f2bf(x4.y), h2 = f2bf(x4.z), h3 = f2bf(x4.w);
        uint2 pk;
        pk.x = (unsigned)h0 | ((unsigned)h1 << 16);
        pk.y = (unsigned)h2 | ((unsigned)h3 << 16);
        *reinterpret_cast<uint2*>(&sX[r][c]) = pk;
    }
    __syncthreads();

    const int l = tid & 63;
    const int w = tid >> 6;
    const int arow = w * 32 + (l & 31);

    // A-fragments: lane holds X[row=l&31][kt*16 + (l>>5)*8 + j], j=0..7
    bf16x8 af[8];
    #pragma unroll
    for (int kt = 0; kt < 8; ++kt)
        af[kt] = *reinterpret_cast<const bf16x8*>(&sX[arow][kt * 16 + (l >> 5) * 8]);

    for (int mat = 0; mat < 2; ++mat) {
        const unsigned short* F = mat ? F2 : F1;
        const float* bias       = mat ? b2 : b1;
        unsigned short* C       = mat ? C2 : C1;
        if (F == nullptr) break;

        #pragma unroll
        for (int ct = 0; ct < 4; ++ct) {
            f32x16 acc = {};
            #pragma unroll
            for (int kt = 0; kt < 8; ++kt) {
                bf16x8 bfr = *reinterpret_cast<const bf16x8*>(F + ((size_t)((ct * 8 + kt) * 64 + l) * 8));
                acc = __builtin_amdgcn_mfma_f32_32x32x16_bf16(af[kt], bfr, acc, 0, 0, 0);
            }
            const int col = ct * 32 + (l & 31);
            const float bb = bias[col];
            #pragma unroll
            for (int reg = 0; reg < 16; ++reg) {
                int r  = (reg & 3) + 8 * (reg >> 2) + 4 * (l >> 5);
                int gr = row0 + w * 32 + r;
                if (gr < n)
                    C[(size_t)gr * D + col] = f2bf(gelu_tanh(acc[reg] + bb));
            }
        }
    }
}

// ---- CSR build ----

__global__ __launch_bounds__(256) void hist_kernel(
    const int* __restrict__ rows, int* __restrict__ cnt, int nE)
{
    int e = blockIdx.x * 256 + threadIdx.x;
    if (e < nE) atomicAdd(&cnt[rows[e]], 1);
}

__global__ __launch_bounds__(1024) void scan_kernel(
    const int* __restrict__ cnt, int* __restrict__ rowptr, int n)
{
    __shared__ int s[1024];
    const int t = threadIdx.x;
    const int C = (n + 1023) >> 10;
    const int lo = t * C;
    const int hi = min(lo + C, n);

    int sum = 0;
    for (int i = lo; i < hi; ++i) sum += cnt[i];
    s[t] = sum;
    __syncthreads();

    for (int off = 1; off < 1024; off <<= 1) {
        int val = (t >= off) ? s[t - off] : 0;
        __syncthreads();
        s[t] += val;
        __syncthreads();
    }

    int run = s[t] - sum;
    for (int i = lo; i < hi; ++i) {
        rowptr[i] = run;
        run += cnt[i];
    }
    if (t == 1023) rowptr[n] = s[1023];
}

__global__ __launch_bounds__(256) void scatter_kernel(
    const int* __restrict__ rows, const int* __restrict__ cols,
    const int* __restrict__ rowptr, int* __restrict__ cur,
    int* __restrict__ colsorted, int nE)
{
    int e = blockIdx.x * 256 + threadIdx.x;
    if (e >= nE) return;
    int r = rows[e];
    int pos = rowptr[r] + atomicAdd(&cur[r], 1);
    colsorted[pos] = cols[e];
}

// ---- aggregation: one wave per row, 4 edges in flight (16 lanes each), bf16 q/k/v ----
__global__ __launch_bounds__(256) void agg_kernel(
    const unsigned short* __restrict__ q, const unsigned short* __restrict__ k,
    const unsigned short* __restrict__ v, const int* __restrict__ rowptr,
    const int* __restrict__ colsorted, float* __restrict__ out, int n)
{
    const int wave = (blockIdx.x * 256 + threadIdx.x) >> 6;
    if (wave >= n) return;
    const int lane = threadIdx.x & 63;
    const int sub  = lane >> 4;     // edge slot 0..3
    const int l    = lane & 15;     // dims l*8 .. l*8+7

    const int r = wave;
    const uint4 qa = *reinterpret_cast<const uint4*>(q + (size_t)r * D + l * 8);
    float qf[8];
    qf[0] = bflo(qa.x); qf[1] = bfhi(qa.x);
    qf[2] = bflo(qa.y); qf[3] = bfhi(qa.y);
    qf[4] = bflo(qa.z); qf[5] = bfhi(qa.z);
    qf[6] = bflo(qa.w); qf[7] = bfhi(qa.w);

    float acc[8] = {0.f,0.f,0.f,0.f,0.f,0.f,0.f,0.f};
    const int start = rowptr[r], end = rowptr[r + 1];

    for (int i = start + sub; i < end; i += 4) {
        const int c = colsorted[i];
        const uint4 ka = *reinterpret_cast<const uint4*>(k + (size_t)c * D + l * 8);
        float dot = qf[0] * bflo(ka.x) + qf[1] * bfhi(ka.x)
                  + qf[2] * bflo(ka.y) + qf[3] * bfhi(ka.y)
                  + qf[4] * bflo(ka.z) + qf[5] * bfhi(ka.z)
                  + qf[6] * bflo(ka.w) + qf[7] * bfhi(ka.w);
        dot += __shfl_xor(dot, 1);
        dot += __shfl_xor(dot, 2);
        dot += __shfl_xor(dot, 4);
        dot += __shfl_xor(dot, 8);
        const float coef = 1.0f / (1.0f + expf(-dot * 0.08838834764831845f));

        const uint4 va = *reinterpret_cast<const uint4*>(v + (size_t)c * D + l * 8);
        acc[0] = fmaf(coef, bflo(va.x), acc[0]);
        acc[1] = fmaf(coef, bfhi(va.x), acc[1]);
        acc[2] = fmaf(coef, bflo(va.y), acc[2]);
        acc[3] = fmaf(coef, bfhi(va.y), acc[3]);
        acc[4] = fmaf(coef, bflo(va.z), acc[4]);
        acc[5] = fmaf(coef, bfhi(va.z), acc[5]);
        acc[6] = fmaf(coef, bflo(va.w), acc[6]);
        acc[7] = fmaf(coef, bfhi(va.w), acc[7]);
    }

    #pragma unroll
    for (int j = 0; j < 8; ++j) {
        acc[j] += __shfl_xor(acc[j], 16);
        acc[j] += __shfl_xor(acc[j], 32);
    }

    if (sub == 0) {
        float* op = out + (size_t)r * D + l * 8;
        float4 o0 = {acc[0], acc[1], acc[2], acc[3]};
        float4 o1 = {acc[4], acc[5], acc[6], acc[7]};
        *reinterpret_cast<float4*>(op)     = o0;
        *reinterpret_cast<float4*>(op + 4) = o1;
    }
}

extern "C" void kernel_launch(void* const* d_in, const int* in_sizes, int n_in,
                              void* d_out, int out_size, void* d_ws, size_t ws_size,
                              hipStream_t stream) {
    const float* query  = (const float*)d_in[0];
    const float* memory = (const float*)d_in[1];
    const float* Wq     = (const float*)d_in[2];
    const float* bq     = (const float*)d_in[3];
    const float* Wk     = (const float*)d_in[4];
    const float* bk     = (const float*)d_in[5];
    const float* Wv     = (const float*)d_in[6];
    const float* bv     = (const float*)d_in[7];
    const int*   erows  = (const int*)d_in[8];
    const int*   ecols  = (const int*)d_in[9];

    const int n  = in_sizes[0] / D;   // 100000
    const int m  = in_sizes[1] / D;   // 100000
    const int nE = in_sizes[8];       // 1600000

    char* base = (char*)d_ws;
    size_t off = 0;
    auto carve = [&](size_t bytes) -> char* {
        char* p = base + off;
        off = (off + bytes + 255) & ~(size_t)255;
        return p;
    };
    unsigned short* q   = (unsigned short*)carve((size_t)n * D * sizeof(unsigned short));
    unsigned short* k   = (unsigned short*)carve((size_t)m * D * sizeof(unsigned short));
    unsigned short* v   = (unsigned short*)carve((size_t)m * D * sizeof(unsigned short));
    unsigned short* Fq  = (unsigned short*)carve(32 * 64 * 8 * sizeof(unsigned short));
    unsigned short* Fk  = (unsigned short*)carve(32 * 64 * 8 * sizeof(unsigned short));
    unsigned short* Fv  = (unsigned short*)carve(32 * 64 * 8 * sizeof(unsigned short));
    int*   rowptr    = (int*)carve((size_t)(n + 1) * sizeof(int));
    int*   cnt       = (int*)carve((size_t)(n + 1) * sizeof(int));
    int*   colsorted = (int*)carve((size_t)nE * sizeof(int));
    float* out       = (float*)d_out;

    dim3 blk(256);

    // W fragment pre-pack (tiny)
    prepack_kernel<<<dim3(64), blk, 0, stream>>>(Wq, Fq);
    prepack_kernel<<<dim3(64), blk, 0, stream>>>(Wk, Fk);
    prepack_kernel<<<dim3(64), blk, 0, stream>>>(Wv, Fv);

    // CSR build
    hipMemsetAsync(cnt, 0, (size_t)(n + 1) * sizeof(int), stream);
    hist_kernel<<<dim3((nE + 255) / 256), blk, 0, stream>>>(erows, cnt, nE);
    scan_kernel<<<dim3(1), dim3(1024), 0, stream>>>(cnt, rowptr, n);
    hipMemsetAsync(cnt, 0, (size_t)(n + 1) * sizeof(int), stream);
    scatter_kernel<<<dim3((nE + 255) / 256), blk, 0, stream>>>(erows, ecols, rowptr, cnt, colsorted, nE);

    // projections: q alone; k,v fused (memory read once)
    const int nb = (n + 127) / 128;
    const int mb = (m + 127) / 128;
    proj_mfma_kernel<<<dim3(nb), blk, 0, stream>>>(query,  Fq, bq, q, nullptr, nullptr, nullptr, n);
    proj_mfma_kernel<<<dim3(mb), blk, 0, stream>>>(memory, Fk, bk, k, Fv, bv, v, m);

    // aggregation: one wave per row, writes all outputs (no out memset needed)
    agg_kernel<<<dim3((n * 64 + 255) / 256), blk, 0, stream>>>(q, k, v, rowptr, colsorted, out, n);
}

// Round 4
// 370.959 us; speedup vs baseline: 15.9099x; 1.4158x over previous
//
#include <hip/hip_runtime.h>
#include <hip/hip_bf16.h>
#include <math.h>

#define D 128

typedef float f32x16 __attribute__((ext_vector_type(16)));
typedef short bf16x8 __attribute__((ext_vector_type(8)));

__device__ __forceinline__ float gelu_tanh(float x) {
    // jax.nn.gelu approximate=True
    float u = 0.7978845608028654f * (x + 0.044715f * x * x * x);
    return 0.5f * x * (1.0f + tanhf(u));
}

__device__ __forceinline__ unsigned short f2bf(float f) {
    union { float f; unsigned u; } x; x.f = f;
    unsigned r = x.u + 0x7fff + ((x.u >> 16) & 1);   // RNE
    return (unsigned short)(r >> 16);
}

__device__ __forceinline__ float bflo(unsigned u) { return __uint_as_float(u << 16); }
__device__ __forceinline__ float bfhi(unsigned u) { return __uint_as_float(u & 0xffff0000u); }

// Pre-pack W[128][128] f32 into B-fragment order for mfma_f32_32x32x16_bf16:
// F[((ct*8+kt)*64+l)*8+j] = bf16(W[(kt*16+(l>>5)*8+j)*128 + ct*32+(l&31)])
__global__ __launch_bounds__(256) void prepack_kernel(
    const float* __restrict__ W, unsigned short* __restrict__ F)
{
    int idx = blockIdx.x * 256 + threadIdx.x;
    if (idx >= 32 * 64 * 8) return;
    int j  = idx & 7;
    int l  = (idx >> 3) & 63;
    int kt = (idx >> 9) & 7;
    int ct = idx >> 12;
    int k  = kt * 16 + (l >> 5) * 8 + j;
    int c  = ct * 32 + (l & 31);
    F[idx] = f2bf(W[k * D + c]);
}

// C[i,:] = bf16(gelu(X[i,:] @ W + b)) for one or two W (shared X read).
__global__ __launch_bounds__(256) void proj_mfma_kernel(
    const float* __restrict__ X,
    const unsigned short* __restrict__ F1, const float* __restrict__ b1,
    unsigned short* __restrict__ C1,
    const unsigned short* __restrict__ F2, const float* __restrict__ b2,
    unsigned short* __restrict__ C2, int n)
{
    __shared__ __align__(16) unsigned short sX[128][136];
    const int tid  = threadIdx.x;
    const int row0 = blockIdx.x * 128;

    #pragma unroll
    for (int p = 0; p < 16; ++p) {
        int flat = p * 256 + tid;
        int r = flat >> 5;
        int c = (flat & 31) * 4;
        int gr = row0 + r; if (gr >= n) gr = n - 1;
        float4 x4 = *reinterpret_cast<const float4*>(X + (size_t)gr * D + c);
        unsigned short h0 = f2bf(x4.x), h1 = f2bf(x4.y), h2 = f2bf(x4.z), h3 = f2bf(x4.w);
        uint2 pk;
        pk.x = (unsigned)h0 | ((unsigned)h1 << 16);
        pk.y = (unsigned)h2 | ((unsigned)h3 << 16);
        *reinterpret_cast<uint2*>(&sX[r][c]) = pk;
    }
    __syncthreads();

    const int l = tid & 63;
    const int w = tid >> 6;
    const int arow = w * 32 + (l & 31);

    bf16x8 af[8];
    #pragma unroll
    for (int kt = 0; kt < 8; ++kt)
        af[kt] = *reinterpret_cast<const bf16x8*>(&sX[arow][kt * 16 + (l >> 5) * 8]);

    for (int mat = 0; mat < 2; ++mat) {
        const unsigned short* F = mat ? F2 : F1;
        const float* bias       = mat ? b2 : b1;
        unsigned short* C       = mat ? C2 : C1;
        if (F == nullptr) break;

        #pragma unroll
        for (int ct = 0; ct < 4; ++ct) {
            f32x16 acc = {};
            #pragma unroll
            for (int kt = 0; kt < 8; ++kt) {
                bf16x8 bfr = *reinterpret_cast<const bf16x8*>(F + ((size_t)((ct * 8 + kt) * 64 + l) * 8));
                acc = __builtin_amdgcn_mfma_f32_32x32x16_bf16(af[kt], bfr, acc, 0, 0, 0);
            }
            const int col = ct * 32 + (l & 31);
            const float bb = bias[col];
            #pragma unroll
            for (int reg = 0; reg < 16; ++reg) {
                int r  = (reg & 3) + 8 * (reg >> 2) + 4 * (l >> 5);
                int gr = row0 + w * 32 + r;
                if (gr < n)
                    C[(size_t)gr * D + col] = f2bf(gelu_tanh(acc[reg] + bb));
            }
        }
    }
}

// ---- CSR build ----

__global__ __launch_bounds__(256) void hist_kernel(
    const int* __restrict__ rows, int* __restrict__ cnt, int nE)
{
    int e = blockIdx.x * 256 + threadIdx.x;
    if (e < nE) atomicAdd(&cnt[rows[e]], 1);
}

// 3-kernel parallel exclusive scan of cnt[0..n-1] -> rowptr[0..n]
// assumes n <= 256*1024 (blocks of 1024 elements, <=256 blocks)
__global__ __launch_bounds__(256) void scan_bsum_kernel(
    const int* __restrict__ cnt, int* __restrict__ bsum, int n)
{
    __shared__ int s[256];
    const int t = threadIdx.x;
    const int base = blockIdx.x * 1024 + t * 4;
    int sum = 0;
    if (base + 3 < n) {
        int4 c4 = *reinterpret_cast<const int4*>(cnt + base);
        sum = c4.x + c4.y + c4.z + c4.w;
    } else {
        for (int i = 0; i < 4; ++i) if (base + i < n) sum += cnt[base + i];
    }
    s[t] = sum;
    __syncthreads();
    #pragma unroll
    for (int off = 128; off > 0; off >>= 1) {
        if (t < off) s[t] += s[t + off];
        __syncthreads();
    }
    if (t == 0) bsum[blockIdx.x] = s[0];
}

__global__ __launch_bounds__(256) void scan_boff_kernel(
    const int* __restrict__ bsum, int* __restrict__ boff,
    int nb, int* __restrict__ total)
{
    __shared__ int s[256];
    const int t = threadIdx.x;
    const int val = (t < nb) ? bsum[t] : 0;
    s[t] = val;
    __syncthreads();
    #pragma unroll
    for (int off = 1; off < 256; off <<= 1) {
        int v = (t >= off) ? s[t - off] : 0;
        __syncthreads();
        s[t] += v;
        __syncthreads();
    }
    if (t < nb) boff[t] = s[t] - val;   // exclusive
    if (t == 255) *total = s[255];
}

__global__ __launch_bounds__(256) void scan_write_kernel(
    const int* __restrict__ cnt, const int* __restrict__ boff,
    int* __restrict__ rowptr, int n)
{
    __shared__ int s[256];
    const int t = threadIdx.x;
    const int base = blockIdx.x * 1024 + t * 4;
    int c[4] = {0, 0, 0, 0};
    if (base + 3 < n) {
        int4 c4 = *reinterpret_cast<const int4*>(cnt + base);
        c[0] = c4.x; c[1] = c4.y; c[2] = c4.z; c[3] = c4.w;
    } else {
        for (int i = 0; i < 4; ++i) if (base + i < n) c[i] = cnt[base + i];
    }
    const int tsum = c[0] + c[1] + c[2] + c[3];
    s[t] = tsum;
    __syncthreads();
    #pragma unroll
    for (int off = 1; off < 256; off <<= 1) {
        int v = (t >= off) ? s[t - off] : 0;
        __syncthreads();
        s[t] += v;
        __syncthreads();
    }
    int run = boff[blockIdx.x] + s[t] - tsum;   // exclusive prefix of this thread
    int w0 = run;
    int w1 = run + c[0];
    int w2 = w1 + c[1];
    int w3 = w2 + c[2];
    if (base + 3 < n) {
        *reinterpret_cast<int4*>(rowptr + base) = make_int4(w0, w1, w2, w3);
    } else {
        int w[4] = {w0, w1, w2, w3};
        for (int i = 0; i < 4; ++i) if (base + i < n) rowptr[base + i] = w[i];
    }
}

__global__ __launch_bounds__(256) void scatter_kernel(
    const int* __restrict__ rows, const int* __restrict__ cols,
    const int* __restrict__ rowptr, int* __restrict__ cur,
    int* __restrict__ colsorted, int nE)
{
    int e = blockIdx.x * 256 + threadIdx.x;
    if (e >= nE) return;
    int r = rows[e];
    int pos = rowptr[r] + atomicAdd(&cur[r], 1);
    colsorted[pos] = cols[e];
}

// ---- aggregation: one wave per row, 4 edges in flight (16 lanes each), bf16 q/k/v ----
__global__ __launch_bounds__(256) void agg_kernel(
    const unsigned short* __restrict__ q, const unsigned short* __restrict__ k,
    const unsigned short* __restrict__ v, const int* __restrict__ rowptr,
    const int* __restrict__ colsorted, float* __restrict__ out, int n)
{
    const int wave = (blockIdx.x * 256 + threadIdx.x) >> 6;
    if (wave >= n) return;
    const int lane = threadIdx.x & 63;
    const int sub  = lane >> 4;
    const int l    = lane & 15;

    const int r = wave;
    const uint4 qa = *reinterpret_cast<const uint4*>(q + (size_t)r * D + l * 8);
    float qf[8];
    qf[0] = bflo(qa.x); qf[1] = bfhi(qa.x);
    qf[2] = bflo(qa.y); qf[3] = bfhi(qa.y);
    qf[4] = bflo(qa.z); qf[5] = bfhi(qa.z);
    qf[6] = bflo(qa.w); qf[7] = bfhi(qa.w);

    float acc[8] = {0.f,0.f,0.f,0.f,0.f,0.f,0.f,0.f};
    const int start = rowptr[r], end = rowptr[r + 1];

    for (int i = start + sub; i < end; i += 4) {
        const int c = colsorted[i];
        const uint4 ka = *reinterpret_cast<const uint4*>(k + (size_t)c * D + l * 8);
        float dot = qf[0] * bflo(ka.x) + qf[1] * bfhi(ka.x)
                  + qf[2] * bflo(ka.y) + qf[3] * bfhi(ka.y)
                  + qf[4] * bflo(ka.z) + qf[5] * bfhi(ka.z)
                  + qf[6] * bflo(ka.w) + qf[7] * bfhi(ka.w);
        dot += __shfl_xor(dot, 1);
        dot += __shfl_xor(dot, 2);
        dot += __shfl_xor(dot, 4);
        dot += __shfl_xor(dot, 8);
        const float coef = 1.0f / (1.0f + expf(-dot * 0.08838834764831845f));

        const uint4 va = *reinterpret_cast<const uint4*>(v + (size_t)c * D + l * 8);
        acc[0] = fmaf(coef, bflo(va.x), acc[0]);
        acc[1] = fmaf(coef, bfhi(va.x), acc[1]);
        acc[2] = fmaf(coef, bflo(va.y), acc[2]);
        acc[3] = fmaf(coef, bfhi(va.y), acc[3]);
        acc[4] = fmaf(coef, bflo(va.z), acc[4]);
        acc[5] = fmaf(coef, bfhi(va.z), acc[5]);
        acc[6] = fmaf(coef, bflo(va.w), acc[6]);
        acc[7] = fmaf(coef, bfhi(va.w), acc[7]);
    }

    #pragma unroll
    for (int j = 0; j < 8; ++j) {
        acc[j] += __shfl_xor(acc[j], 16);
        acc[j] += __shfl_xor(acc[j], 32);
    }

    if (sub == 0) {
        float* op = out + (size_t)r * D + l * 8;
        float4 o0 = {acc[0], acc[1], acc[2], acc[3]};
        float4 o1 = {acc[4], acc[5], acc[6], acc[7]};
        *reinterpret_cast<float4*>(op)     = o0;
        *reinterpret_cast<float4*>(op + 4) = o1;
    }
}

extern "C" void kernel_launch(void* const* d_in, const int* in_sizes, int n_in,
                              void* d_out, int out_size, void* d_ws, size_t ws_size,
                              hipStream_t stream) {
    const float* query  = (const float*)d_in[0];
    const float* memory = (const float*)d_in[1];
    const float* Wq     = (const float*)d_in[2];
    const float* bq     = (const float*)d_in[3];
    const float* Wk     = (const float*)d_in[4];
    const float* bk     = (const float*)d_in[5];
    const float* Wv     = (const float*)d_in[6];
    const float* bv     = (const float*)d_in[7];
    const int*   erows  = (const int*)d_in[8];
    const int*   ecols  = (const int*)d_in[9];

    const int n  = in_sizes[0] / D;   // 100000
    const int m  = in_sizes[1] / D;   // 100000
    const int nE = in_sizes[8];       // 1600000

    char* base = (char*)d_ws;
    size_t off = 0;
    auto carve = [&](size_t bytes) -> char* {
        char* p = base + off;
        off = (off + bytes + 255) & ~(size_t)255;
        return p;
    };
    unsigned short* q   = (unsigned short*)carve((size_t)n * D * sizeof(unsigned short));
    unsigned short* k   = (unsigned short*)carve((size_t)m * D * sizeof(unsigned short));
    unsigned short* v   = (unsigned short*)carve((size_t)m * D * sizeof(unsigned short));
    unsigned short* Fq  = (unsigned short*)carve(32 * 64 * 8 * sizeof(unsigned short));
    unsigned short* Fk  = (unsigned short*)carve(32 * 64 * 8 * sizeof(unsigned short));
    unsigned short* Fv  = (unsigned short*)carve(32 * 64 * 8 * sizeof(unsigned short));
    int*   rowptr    = (int*)carve((size_t)(n + 1) * sizeof(int));
    int*   cnt       = (int*)carve((size_t)(n + 1) * sizeof(int));
    int*   bsum      = (int*)carve(256 * sizeof(int));
    int*   boff      = (int*)carve(256 * sizeof(int));
    int*   colsorted = (int*)carve((size_t)nE * sizeof(int));
    float* out       = (float*)d_out;

    dim3 blk(256);
    const int nbScan = (n + 1023) / 1024;   // 98 <= 256

    // W fragment pre-pack (tiny)
    prepack_kernel<<<dim3(64), blk, 0, stream>>>(Wq, Fq);
    prepack_kernel<<<dim3(64), blk, 0, stream>>>(Wk, Fk);
    prepack_kernel<<<dim3(64), blk, 0, stream>>>(Wv, Fv);

    // CSR build
    hipMemsetAsync(cnt, 0, (size_t)(n + 1) * sizeof(int), stream);
    hist_kernel<<<dim3((nE + 255) / 256), blk, 0, stream>>>(erows, cnt, nE);
    scan_bsum_kernel<<<dim3(nbScan), blk, 0, stream>>>(cnt, bsum, n);
    scan_boff_kernel<<<dim3(1), blk, 0, stream>>>(bsum, boff, nbScan, rowptr + n);
    scan_write_kernel<<<dim3(nbScan), blk, 0, stream>>>(cnt, boff, rowptr, n);
    hipMemsetAsync(cnt, 0, (size_t)(n + 1) * sizeof(int), stream);
    scatter_kernel<<<dim3((nE + 255) / 256), blk, 0, stream>>>(erows, ecols, rowptr, cnt, colsorted, nE);

    // projections: q alone; k,v fused (memory read once)
    const int nb = (n + 127) / 128;
    const int mb = (m + 127) / 128;
    proj_mfma_kernel<<<dim3(nb), blk, 0, stream>>>(query,  Fq, bq, q, nullptr, nullptr, nullptr, n);
    proj_mfma_kernel<<<dim3(mb), blk, 0, stream>>>(memory, Fk, bk, k, Fv, bv, v, m);

    // aggregation: one wave per row, writes all outputs (no out memset needed)
    agg_kernel<<<dim3((n * 64 + 255) / 256), blk, 0, stream>>>(q, k, v, rowptr, colsorted, out, n);
}

// Round 5
// 360.468 us; speedup vs baseline: 16.3730x; 1.0291x over previous
//
#include <hip/hip_runtime.h>
#include <hip/hip_bf16.h>
#include <math.h>

#define D 128

typedef float f32x16 __attribute__((ext_vector_type(16)));
typedef short bf16x8 __attribute__((ext_vector_type(8)));

__device__ __forceinline__ float gelu_tanh(float x) {
    // jax.nn.gelu approximate=True
    float u = 0.7978845608028654f * (x + 0.044715f * x * x * x);
    return 0.5f * x * (1.0f + tanhf(u));
}

__device__ __forceinline__ unsigned short f2bf(float f) {
    union { float f; unsigned u; } x; x.f = f;
    unsigned r = x.u + 0x7fff + ((x.u >> 16) & 1);   // RNE
    return (unsigned short)(r >> 16);
}

__device__ __forceinline__ float bflo(unsigned u) { return __uint_as_float(u << 16); }
__device__ __forceinline__ float bfhi(unsigned u) { return __uint_as_float(u & 0xffff0000u); }

// Pre-pack W[128][128] f32 into B-fragment order for mfma_f32_32x32x16_bf16:
// F[((ct*8+kt)*64+l)*8+j] = bf16(W[(kt*16+(l>>5)*8+j)*128 + ct*32+(l&31)])
__global__ __launch_bounds__(256) void prepack_kernel(
    const float* __restrict__ W, unsigned short* __restrict__ F)
{
    int idx = blockIdx.x * 256 + threadIdx.x;
    if (idx >= 32 * 64 * 8) return;
    int j  = idx & 7;
    int l  = (idx >> 3) & 63;
    int kt = (idx >> 9) & 7;
    int ct = idx >> 12;
    int k  = kt * 16 + (l >> 5) * 8 + j;
    int c  = ct * 32 + (l & 31);
    F[idx] = f2bf(W[k * D + c]);
}

// C[i,:] = bf16(gelu(X[i,:] @ W + b)) for one or two W (shared X read).
__global__ __launch_bounds__(256) void proj_mfma_kernel(
    const float* __restrict__ X,
    const unsigned short* __restrict__ F1, const float* __restrict__ b1,
    unsigned short* __restrict__ C1,
    const unsigned short* __restrict__ F2, const float* __restrict__ b2,
    unsigned short* __restrict__ C2, int n)
{
    __shared__ __align__(16) unsigned short sX[128][136];
    const int tid  = threadIdx.x;
    const int row0 = blockIdx.x * 128;

    #pragma unroll
    for (int p = 0; p < 16; ++p) {
        int flat = p * 256 + tid;
        int r = flat >> 5;
        int c = (flat & 31) * 4;
        int gr = row0 + r; if (gr >= n) gr = n - 1;
        float4 x4 = *reinterpret_cast<const float4*>(X + (size_t)gr * D + c);
        unsigned short h0 = f2bf(x4.x), h1 = f2bf(x4.y), h2 = f2bf(x4.z), h3 = f2bf(x4.w);
        uint2 pk;
        pk.x = (unsigned)h0 | ((unsigned)h1 << 16);
        pk.y = (unsigned)h2 | ((unsigned)h3 << 16);
        *reinterpret_cast<uint2*>(&sX[r][c]) = pk;
    }
    __syncthreads();

    const int l = tid & 63;
    const int w = tid >> 6;
    const int arow = w * 32 + (l & 31);

    bf16x8 af[8];
    #pragma unroll
    for (int kt = 0; kt < 8; ++kt)
        af[kt] = *reinterpret_cast<const bf16x8*>(&sX[arow][kt * 16 + (l >> 5) * 8]);

    for (int mat = 0; mat < 2; ++mat) {
        const unsigned short* F = mat ? F2 : F1;
        const float* bias       = mat ? b2 : b1;
        unsigned short* C       = mat ? C2 : C1;
        if (F == nullptr) break;

        #pragma unroll
        for (int ct = 0; ct < 4; ++ct) {
            f32x16 acc = {};
            #pragma unroll
            for (int kt = 0; kt < 8; ++kt) {
                bf16x8 bfr = *reinterpret_cast<const bf16x8*>(F + ((size_t)((ct * 8 + kt) * 64 + l) * 8));
                acc = __builtin_amdgcn_mfma_f32_32x32x16_bf16(af[kt], bfr, acc, 0, 0, 0);
            }
            const int col = ct * 32 + (l & 31);
            const float bb = bias[col];
            #pragma unroll
            for (int reg = 0; reg < 16; ++reg) {
                int r  = (reg & 3) + 8 * (reg >> 2) + 4 * (l >> 5);
                int gr = row0 + w * 32 + r;
                if (gr < n)
                    C[(size_t)gr * D + col] = f2bf(gelu_tanh(acc[reg] + bb));
            }
        }
    }
}

// ---- CSR build (XCD-sliced: group g = blockIdx&7 owns rows [g*n/8,(g+1)*n/8)) ----

__global__ __launch_bounds__(256) void hist_kernel(
    const int* __restrict__ rows, int* __restrict__ cnt, int nE, int n)
{
    const int g  = blockIdx.x & 7;
    const int lo = (int)(((long long)g * n) >> 3);
    const int hi = (int)(((long long)(g + 1) * n) >> 3);
    const int idx = (blockIdx.x >> 3) * 1024 + threadIdx.x * 4;
    if (idx + 3 < nE) {
        int4 r4 = *reinterpret_cast<const int4*>(rows + idx);
        if (r4.x >= lo && r4.x < hi) atomicAdd(&cnt[r4.x], 1);
        if (r4.y >= lo && r4.y < hi) atomicAdd(&cnt[r4.y], 1);
        if (r4.z >= lo && r4.z < hi) atomicAdd(&cnt[r4.z], 1);
        if (r4.w >= lo && r4.w < hi) atomicAdd(&cnt[r4.w], 1);
    } else {
        for (int i = 0; i < 4; ++i)
            if (idx + i < nE) {
                int r = rows[idx + i];
                if (r >= lo && r < hi) atomicAdd(&cnt[r], 1);
            }
    }
}

// 3-kernel parallel exclusive scan of cnt[0..n-1] -> rowptr[0..n]
__global__ __launch_bounds__(256) void scan_bsum_kernel(
    const int* __restrict__ cnt, int* __restrict__ bsum, int n)
{
    __shared__ int s[256];
    const int t = threadIdx.x;
    const int base = blockIdx.x * 1024 + t * 4;
    int sum = 0;
    if (base + 3 < n) {
        int4 c4 = *reinterpret_cast<const int4*>(cnt + base);
        sum = c4.x + c4.y + c4.z + c4.w;
    } else {
        for (int i = 0; i < 4; ++i) if (base + i < n) sum += cnt[base + i];
    }
    s[t] = sum;
    __syncthreads();
    #pragma unroll
    for (int off = 128; off > 0; off >>= 1) {
        if (t < off) s[t] += s[t + off];
        __syncthreads();
    }
    if (t == 0) bsum[blockIdx.x] = s[0];
}

__global__ __launch_bounds__(256) void scan_boff_kernel(
    const int* __restrict__ bsum, int* __restrict__ boff,
    int nb, int* __restrict__ total)
{
    __shared__ int s[256];
    const int t = threadIdx.x;
    const int val = (t < nb) ? bsum[t] : 0;
    s[t] = val;
    __syncthreads();
    #pragma unroll
    for (int off = 1; off < 256; off <<= 1) {
        int v = (t >= off) ? s[t - off] : 0;
        __syncthreads();
        s[t] += v;
        __syncthreads();
    }
    if (t < nb) boff[t] = s[t] - val;   // exclusive
    if (t == 255) *total = s[255];
}

__global__ __launch_bounds__(256) void scan_write_kernel(
    const int* __restrict__ cnt, const int* __restrict__ boff,
    int* __restrict__ rowptr, int n)
{
    __shared__ int s[256];
    const int t = threadIdx.x;
    const int base = blockIdx.x * 1024 + t * 4;
    int c[4] = {0, 0, 0, 0};
    if (base + 3 < n) {
        int4 c4 = *reinterpret_cast<const int4*>(cnt + base);
        c[0] = c4.x; c[1] = c4.y; c[2] = c4.z; c[3] = c4.w;
    } else {
        for (int i = 0; i < 4; ++i) if (base + i < n) c[i] = cnt[base + i];
    }
    const int tsum = c[0] + c[1] + c[2] + c[3];
    s[t] = tsum;
    __syncthreads();
    #pragma unroll
    for (int off = 1; off < 256; off <<= 1) {
        int v = (t >= off) ? s[t - off] : 0;
        __syncthreads();
        s[t] += v;
        __syncthreads();
    }
    int run = boff[blockIdx.x] + s[t] - tsum;
    int w0 = run;
    int w1 = run + c[0];
    int w2 = w1 + c[1];
    int w3 = w2 + c[2];
    if (base + 3 < n) {
        *reinterpret_cast<int4*>(rowptr + base) = make_int4(w0, w1, w2, w3);
    } else {
        int w[4] = {w0, w1, w2, w3};
        for (int i = 0; i < 4; ++i) if (base + i < n) rowptr[base + i] = w[i];
    }
}

// cur[] pre-initialized to rowptr[0..n-1] (d2d copy); slice-filtered like hist.
__global__ __launch_bounds__(256) void scatter_kernel(
    const int* __restrict__ rows, const int* __restrict__ cols,
    int* __restrict__ cur, int* __restrict__ colsorted, int nE, int n)
{
    const int g  = blockIdx.x & 7;
    const int lo = (int)(((long long)g * n) >> 3);
    const int hi = (int)(((long long)(g + 1) * n) >> 3);
    const int idx = (blockIdx.x >> 3) * 1024 + threadIdx.x * 4;
    if (idx + 3 < nE) {
        int4 r4 = *reinterpret_cast<const int4*>(rows + idx);
        int4 c4 = *reinterpret_cast<const int4*>(cols + idx);
        if (r4.x >= lo && r4.x < hi) colsorted[atomicAdd(&cur[r4.x], 1)] = c4.x;
        if (r4.y >= lo && r4.y < hi) colsorted[atomicAdd(&cur[r4.y], 1)] = c4.y;
        if (r4.z >= lo && r4.z < hi) colsorted[atomicAdd(&cur[r4.z], 1)] = c4.z;
        if (r4.w >= lo && r4.w < hi) colsorted[atomicAdd(&cur[r4.w], 1)] = c4.w;
    } else {
        for (int i = 0; i < 4; ++i)
            if (idx + i < nE) {
                int r = rows[idx + i];
                if (r >= lo && r < hi)
                    colsorted[atomicAdd(&cur[r], 1)] = cols[idx + i];
            }
    }
}

// ---- aggregation: one wave per row, 4 edges in flight (16 lanes each), bf16 q/k/v ----
__global__ __launch_bounds__(256) void agg_kernel(
    const unsigned short* __restrict__ q, const unsigned short* __restrict__ k,
    const unsigned short* __restrict__ v, const int* __restrict__ rowptr,
    const int* __restrict__ colsorted, float* __restrict__ out, int n)
{
    const int wave = (blockIdx.x * 256 + threadIdx.x) >> 6;
    if (wave >= n) return;
    const int lane = threadIdx.x & 63;
    const int sub  = lane >> 4;
    const int l    = lane & 15;

    const int r = wave;
    const uint4 qa = *reinterpret_cast<const uint4*>(q + (size_t)r * D + l * 8);
    float qf[8];
    qf[0] = bflo(qa.x); qf[1] = bfhi(qa.x);
    qf[2] = bflo(qa.y); qf[3] = bfhi(qa.y);
    qf[4] = bflo(qa.z); qf[5] = bfhi(qa.z);
    qf[6] = bflo(qa.w); qf[7] = bfhi(qa.w);

    float acc[8] = {0.f,0.f,0.f,0.f,0.f,0.f,0.f,0.f};
    const int start = rowptr[r], end = rowptr[r + 1];

    for (int i = start + sub; i < end; i += 4) {
        const int c = colsorted[i];
        const uint4 ka = *reinterpret_cast<const uint4*>(k + (size_t)c * D + l * 8);
        float dot = qf[0] * bflo(ka.x) + qf[1] * bfhi(ka.x)
                  + qf[2] * bflo(ka.y) + qf[3] * bfhi(ka.y)
                  + qf[4] * bflo(ka.z) + qf[5] * bfhi(ka.z)
                  + qf[6] * bflo(ka.w) + qf[7] * bfhi(ka.w);
        dot += __shfl_xor(dot, 1);
        dot += __shfl_xor(dot, 2);
        dot += __shfl_xor(dot, 4);
        dot += __shfl_xor(dot, 8);
        const float coef = 1.0f / (1.0f + expf(-dot * 0.08838834764831845f));

        const uint4 va = *reinterpret_cast<const uint4*>(v + (size_t)c * D + l * 8);
        acc[0] = fmaf(coef, bflo(va.x), acc[0]);
        acc[1] = fmaf(coef, bfhi(va.x), acc[1]);
        acc[2] = fmaf(coef, bflo(va.y), acc[2]);
        acc[3] = fmaf(coef, bfhi(va.y), acc[3]);
        acc[4] = fmaf(coef, bflo(va.z), acc[4]);
        acc[5] = fmaf(coef, bfhi(va.z), acc[5]);
        acc[6] = fmaf(coef, bflo(va.w), acc[6]);
        acc[7] = fmaf(coef, bfhi(va.w), acc[7]);
    }

    #pragma unroll
    for (int j = 0; j < 8; ++j) {
        acc[j] += __shfl_xor(acc[j], 16);
        acc[j] += __shfl_xor(acc[j], 32);
    }

    if (sub == 0) {
        float* op = out + (size_t)r * D + l * 8;
        float4 o0 = {acc[0], acc[1], acc[2], acc[3]};
        float4 o1 = {acc[4], acc[5], acc[6], acc[7]};
        *reinterpret_cast<float4*>(op)     = o0;
        *reinterpret_cast<float4*>(op + 4) = o1;
    }
}

extern "C" void kernel_launch(void* const* d_in, const int* in_sizes, int n_in,
                              void* d_out, int out_size, void* d_ws, size_t ws_size,
                              hipStream_t stream) {
    const float* query  = (const float*)d_in[0];
    const float* memory = (const float*)d_in[1];
    const float* Wq     = (const float*)d_in[2];
    const float* bq     = (const float*)d_in[3];
    const float* Wk     = (const float*)d_in[4];
    const float* bk     = (const float*)d_in[5];
    const float* Wv     = (const float*)d_in[6];
    const float* bv     = (const float*)d_in[7];
    const int*   erows  = (const int*)d_in[8];
    const int*   ecols  = (const int*)d_in[9];

    const int n  = in_sizes[0] / D;   // 100000
    const int m  = in_sizes[1] / D;   // 100000
    const int nE = in_sizes[8];       // 1600000

    char* base = (char*)d_ws;
    size_t off = 0;
    auto carve = [&](size_t bytes) -> char* {
        char* p = base + off;
        off = (off + bytes + 255) & ~(size_t)255;
        return p;
    };
    unsigned short* q   = (unsigned short*)carve((size_t)n * D * sizeof(unsigned short));
    unsigned short* k   = (unsigned short*)carve((size_t)m * D * sizeof(unsigned short));
    unsigned short* v   = (unsigned short*)carve((size_t)m * D * sizeof(unsigned short));
    unsigned short* Fq  = (unsigned short*)carve(32 * 64 * 8 * sizeof(unsigned short));
    unsigned short* Fk  = (unsigned short*)carve(32 * 64 * 8 * sizeof(unsigned short));
    unsigned short* Fv  = (unsigned short*)carve(32 * 64 * 8 * sizeof(unsigned short));
    int*   rowptr    = (int*)carve((size_t)(n + 1) * sizeof(int));
    int*   cnt       = (int*)carve((size_t)(n + 1) * sizeof(int));
    int*   bsum      = (int*)carve(256 * sizeof(int));
    int*   boff      = (int*)carve(256 * sizeof(int));
    int*   colsorted = (int*)carve((size_t)nE * sizeof(int));
    float* out       = (float*)d_out;

    dim3 blk(256);
    const int nbScan  = (n + 1023) / 1024;            // <=256
    const int nbEdge8 = ((nE + 1023) / 1024) * 8;     // sliced edge kernels

    // W fragment pre-pack (tiny)
    prepack_kernel<<<dim3(64), blk, 0, stream>>>(Wq, Fq);
    prepack_kernel<<<dim3(64), blk, 0, stream>>>(Wk, Fk);
    prepack_kernel<<<dim3(64), blk, 0, stream>>>(Wv, Fv);

    // CSR build
    hipMemsetAsync(cnt, 0, (size_t)(n + 1) * sizeof(int), stream);
    hist_kernel<<<dim3(nbEdge8), blk, 0, stream>>>(erows, cnt, nE, n);
    scan_bsum_kernel<<<dim3(nbScan), blk, 0, stream>>>(cnt, bsum, n);
    scan_boff_kernel<<<dim3(1), blk, 0, stream>>>(bsum, boff, nbScan, rowptr + n);
    scan_write_kernel<<<dim3(nbScan), blk, 0, stream>>>(cnt, boff, rowptr, n);
    // cur := rowptr[0..n-1] (reuse cnt), then scatter appends in-place
    hipMemcpyAsync(cnt, rowptr, (size_t)n * sizeof(int), hipMemcpyDeviceToDevice, stream);
    scatter_kernel<<<dim3(nbEdge8), blk, 0, stream>>>(erows, ecols, cnt, colsorted, nE, n);

    // projections: q alone; k,v fused (memory read once)
    const int nb = (n + 127) / 128;
    const int mb = (m + 127) / 128;
    proj_mfma_kernel<<<dim3(nb), blk, 0, stream>>>(query,  Fq, bq, q, nullptr, nullptr, nullptr, n);
    proj_mfma_kernel<<<dim3(mb), blk, 0, stream>>>(memory, Fk, bk, k, Fv, bv, v, m);

    // aggregation: one wave per row, writes all outputs (no out memset needed)
    agg_kernel<<<dim3((n * 64 + 255) / 256), blk, 0, stream>>>(q, k, v, rowptr, colsorted, out, n);
}

// Round 7
// 343.798 us; speedup vs baseline: 17.1669x; 1.0485x over previous
//
#include <hip/hip_runtime.h>
#include <hip/hip_bf16.h>
#include <math.h>

#ifndef __has_builtin
#define __has_builtin(x) 0
#endif
#if __has_builtin(__builtin_amdgcn_cvt_pk_fp8_f32) && __has_builtin(__builtin_amdgcn_cvt_pk_f32_fp8)
#define FP8_HW 1
#else
#include <hip/hip_fp8.h>
#endif

#define D 128
#define KVREC 384   // 128 B k (fp8 e4m3) + 256 B v (bf16)

typedef float f32x16 __attribute__((ext_vector_type(16)));
typedef float f32x2  __attribute__((ext_vector_type(2)));
typedef short bf16x8 __attribute__((ext_vector_type(8)));

__device__ __forceinline__ float gelu_tanh(float x) {
    // jax.nn.gelu approximate=True
    float u = 0.7978845608028654f * (x + 0.044715f * x * x * x);
    return 0.5f * x * (1.0f + tanhf(u));
}

__device__ __forceinline__ unsigned short f2bf(float f) {
    union { float f; unsigned u; } x; x.f = f;
    unsigned r = x.u + 0x7fff + ((x.u >> 16) & 1);   // RNE
    return (unsigned short)(r >> 16);
}

__device__ __forceinline__ float bflo(unsigned u) { return __uint_as_float(u << 16); }
__device__ __forceinline__ float bfhi(unsigned u) { return __uint_as_float(u & 0xffff0000u); }

// fp8 e4m3 (OCP) encode/decode via HW converts
__device__ __forceinline__ unsigned char f2fp8(float x) {
#ifdef FP8_HW
    return (unsigned char)(__builtin_amdgcn_cvt_pk_fp8_f32(x, x, 0, false) & 0xFF);
#else
    __hip_fp8_e4m3 h(x); return (unsigned char)h.__x;
#endif
}

__device__ __forceinline__ void fp8x4d(unsigned u, float* f) {
#ifdef FP8_HW
    f32x2 lo = __builtin_amdgcn_cvt_pk_f32_fp8((int)u, false);
    f32x2 hi = __builtin_amdgcn_cvt_pk_f32_fp8((int)u, true);
    f[0] = lo[0]; f[1] = lo[1]; f[2] = hi[0]; f[3] = hi[1];
#else
    #pragma unroll
    for (int i = 0; i < 4; ++i) {
        __hip_fp8_e4m3 h; h.__x = (unsigned char)((u >> (8 * i)) & 0xFF);
        f[i] = (float)h;
    }
#endif
}

// Pre-pack 3 W[128][128] f32 into B-fragment order for mfma_f32_32x32x16_bf16:
// F[((ct*8+kt)*64+l)*8+j] = bf16(W[(kt*16+(l>>5)*8+j)*128 + ct*32+(l&31)])
__global__ __launch_bounds__(256) void prepack3_kernel(
    const float* __restrict__ W0, const float* __restrict__ W1,
    const float* __restrict__ W2, unsigned short* __restrict__ F)
{
    int gidx = blockIdx.x * 256 + threadIdx.x;
    if (gidx >= 3 * 32 * 64 * 8) return;
    const int midx = gidx >> 14;               // which matrix
    const int idx  = gidx & 16383;
    const float* W = midx == 0 ? W0 : (midx == 1 ? W1 : W2);
    int j  = idx & 7;
    int l  = (idx >> 3) & 63;
    int kt = (idx >> 9) & 7;
    int ct = idx >> 12;
    int k  = kt * 16 + (l >> 5) * 8 + j;
    int c  = ct * 32 + (l & 31);
    F[gidx] = f2bf(W[k * D + c]);
}

// q[i,:] = bf16(gelu(X[i,:] @ Wq + bq))
__global__ __launch_bounds__(256) void proj_q_kernel(
    const float* __restrict__ X,
    const unsigned short* __restrict__ F1, const float* __restrict__ b1,
    unsigned short* __restrict__ C1, int n)
{
    __shared__ __align__(16) unsigned short sX[128][136];
    const int tid  = threadIdx.x;
    const int row0 = blockIdx.x * 128;

    #pragma unroll
    for (int p = 0; p < 16; ++p) {
        int flat = p * 256 + tid;
        int r = flat >> 5;
        int c = (flat & 31) * 4;
        int gr = row0 + r; if (gr >= n) gr = n - 1;
        float4 x4 = *reinterpret_cast<const float4*>(X + (size_t)gr * D + c);
        uint2 pk;
        pk.x = (unsigned)f2bf(x4.x) | ((unsigned)f2bf(x4.y) << 16);
        pk.y = (unsigned)f2bf(x4.z) | ((unsigned)f2bf(x4.w) << 16);
        *reinterpret_cast<uint2*>(&sX[r][c]) = pk;
    }
    __syncthreads();

    const int l = tid & 63;
    const int w = tid >> 6;
    const int arow = w * 32 + (l & 31);

    bf16x8 af[8];
    #pragma unroll
    for (int kt = 0; kt < 8; ++kt)
        af[kt] = *reinterpret_cast<const bf16x8*>(&sX[arow][kt * 16 + (l >> 5) * 8]);

    #pragma unroll
    for (int ct = 0; ct < 4; ++ct) {
        f32x16 acc = {};
        #pragma unroll
        for (int kt = 0; kt < 8; ++kt) {
            bf16x8 bfr = *reinterpret_cast<const bf16x8*>(F1 + ((size_t)((ct * 8 + kt) * 64 + l) * 8));
            acc = __builtin_amdgcn_mfma_f32_32x32x16_bf16(af[kt], bfr, acc, 0, 0, 0);
        }
        const int col = ct * 32 + (l & 31);
        const float bb = b1[col];
        #pragma unroll
        for (int reg = 0; reg < 16; ++reg) {
            int r  = (reg & 3) + 8 * (reg >> 2) + 4 * (l >> 5);
            int gr = row0 + w * 32 + r;
            if (gr < n)
                C1[(size_t)gr * D + col] = f2bf(gelu_tanh(acc[reg] + bb));
        }
    }
}

// kv record [i]: bytes 0..127  = fp8(gelu(X@Wk+bk))   (k)
//                bytes 128..383 = bf16(gelu(X@Wv+bv))  (v)
__global__ __launch_bounds__(256) void proj_kv_kernel(
    const float* __restrict__ X,
    const unsigned short* __restrict__ Fk, const float* __restrict__ bk,
    const unsigned short* __restrict__ Fv, const float* __restrict__ bv,
    unsigned char* __restrict__ kv, int n)
{
    __shared__ __align__(16) unsigned short sX[128][136];
    const int tid  = threadIdx.x;
    const int row0 = blockIdx.x * 128;

    #pragma unroll
    for (int p = 0; p < 16; ++p) {
        int flat = p * 256 + tid;
        int r = flat >> 5;
        int c = (flat & 31) * 4;
        int gr = row0 + r; if (gr >= n) gr = n - 1;
        float4 x4 = *reinterpret_cast<const float4*>(X + (size_t)gr * D + c);
        uint2 pk;
        pk.x = (unsigned)f2bf(x4.x) | ((unsigned)f2bf(x4.y) << 16);
        pk.y = (unsigned)f2bf(x4.z) | ((unsigned)f2bf(x4.w) << 16);
        *reinterpret_cast<uint2*>(&sX[r][c]) = pk;
    }
    __syncthreads();

    const int l = tid & 63;
    const int w = tid >> 6;
    const int arow = w * 32 + (l & 31);

    bf16x8 af[8];
    #pragma unroll
    for (int kt = 0; kt < 8; ++kt)
        af[kt] = *reinterpret_cast<const bf16x8*>(&sX[arow][kt * 16 + (l >> 5) * 8]);

    for (int mat = 0; mat < 2; ++mat) {
        const unsigned short* F = mat ? Fv : Fk;
        const float* bias       = mat ? bv : bk;

        #pragma unroll
        for (int ct = 0; ct < 4; ++ct) {
            f32x16 acc = {};
            #pragma unroll
            for (int kt = 0; kt < 8; ++kt) {
                bf16x8 bfr = *reinterpret_cast<const bf16x8*>(F + ((size_t)((ct * 8 + kt) * 64 + l) * 8));
                acc = __builtin_amdgcn_mfma_f32_32x32x16_bf16(af[kt], bfr, acc, 0, 0, 0);
            }
            const int col = ct * 32 + (l & 31);
            const float bb = bias[col];
            #pragma unroll
            for (int reg = 0; reg < 16; ++reg) {
                int r  = (reg & 3) + 8 * (reg >> 2) + 4 * (l >> 5);
                int gr = row0 + w * 32 + r;
                if (gr < n) {
                    unsigned char* rec = kv + (size_t)gr * KVREC;
                    float val = gelu_tanh(acc[reg] + bb);
                    if (mat == 0)
                        rec[col] = f2fp8(val);
                    else
                        reinterpret_cast<unsigned short*>(rec + 128)[col] = f2bf(val);
                }
            }
        }
    }
}

// ---- CSR build (XCD-sliced: group g = blockIdx&7 owns rows [g*n/8,(g+1)*n/8)) ----

__global__ __launch_bounds__(256) void hist_kernel(
    const int* __restrict__ rows, int* __restrict__ cnt, int nE, int n)
{
    const int g  = blockIdx.x & 7;
    const int lo = (int)(((long long)g * n) >> 3);
    const int hi = (int)(((long long)(g + 1) * n) >> 3);
    const int idx = (blockIdx.x >> 3) * 1024 + threadIdx.x * 4;
    if (idx + 3 < nE) {
        int4 r4 = *reinterpret_cast<const int4*>(rows + idx);
        if (r4.x >= lo && r4.x < hi) atomicAdd(&cnt[r4.x], 1);
        if (r4.y >= lo && r4.y < hi) atomicAdd(&cnt[r4.y], 1);
        if (r4.z >= lo && r4.z < hi) atomicAdd(&cnt[r4.z], 1);
        if (r4.w >= lo && r4.w < hi) atomicAdd(&cnt[r4.w], 1);
    } else {
        for (int i = 0; i < 4; ++i)
            if (idx + i < nE) {
                int r = rows[idx + i];
                if (r >= lo && r < hi) atomicAdd(&cnt[r], 1);
            }
    }
}

// 3-kernel parallel exclusive scan of cnt[0..n-1] -> rowptr[0..n]
__global__ __launch_bounds__(256) void scan_bsum_kernel(
    const int* __restrict__ cnt, int* __restrict__ bsum, int n)
{
    __shared__ int s[256];
    const int t = threadIdx.x;
    const int base = blockIdx.x * 1024 + t * 4;
    int sum = 0;
    if (base + 3 < n) {
        int4 c4 = *reinterpret_cast<const int4*>(cnt + base);
        sum = c4.x + c4.y + c4.z + c4.w;
    } else {
        for (int i = 0; i < 4; ++i) if (base + i < n) sum += cnt[base + i];
    }
    s[t] = sum;
    __syncthreads();
    #pragma unroll
    for (int off = 128; off > 0; off >>= 1) {
        if (t < off) s[t] += s[t + off];
        __syncthreads();
    }
    if (t == 0) bsum[blockIdx.x] = s[0];
}

__global__ __launch_bounds__(256) void scan_boff_kernel(
    const int* __restrict__ bsum, int* __restrict__ boff,
    int nb, int* __restrict__ total)
{
    __shared__ int s[256];
    const int t = threadIdx.x;
    const int val = (t < nb) ? bsum[t] : 0;
    s[t] = val;
    __syncthreads();
    #pragma unroll
    for (int off = 1; off < 256; off <<= 1) {
        int v = (t >= off) ? s[t - off] : 0;
        __syncthreads();
        s[t] += v;
        __syncthreads();
    }
    if (t < nb) boff[t] = s[t] - val;   // exclusive
    if (t == 255) *total = s[255];
}

__global__ __launch_bounds__(256) void scan_write_kernel(
    const int* __restrict__ cnt, const int* __restrict__ boff,
    int* __restrict__ rowptr, int n)
{
    __shared__ int s[256];
    const int t = threadIdx.x;
    const int base = blockIdx.x * 1024 + t * 4;
    int c[4] = {0, 0, 0, 0};
    if (base + 3 < n) {
        int4 c4 = *reinterpret_cast<const int4*>(cnt + base);
        c[0] = c4.x; c[1] = c4.y; c[2] = c4.z; c[3] = c4.w;
    } else {
        for (int i = 0; i < 4; ++i) if (base + i < n) c[i] = cnt[base + i];
    }
    const int tsum = c[0] + c[1] + c[2] + c[3];
    s[t] = tsum;
    __syncthreads();
    #pragma unroll
    for (int off = 1; off < 256; off <<= 1) {
        int v = (t >= off) ? s[t - off] : 0;
        __syncthreads();
        s[t] += v;
        __syncthreads();
    }
    int run = boff[blockIdx.x] + s[t] - tsum;
    int w0 = run;
    int w1 = run + c[0];
    int w2 = w1 + c[1];
    int w3 = w2 + c[2];
    if (base + 3 < n) {
        *reinterpret_cast<int4*>(rowptr + base) = make_int4(w0, w1, w2, w3);
    } else {
        int w[4] = {w0, w1, w2, w3};
        for (int i = 0; i < 4; ++i) if (base + i < n) rowptr[base + i] = w[i];
    }
}

// cur[] pre-initialized to rowptr[0..n-1] (d2d copy); slice-filtered like hist.
__global__ __launch_bounds__(256) void scatter_kernel(
    const int* __restrict__ rows, const int* __restrict__ cols,
    int* __restrict__ cur, int* __restrict__ colsorted, int nE, int n)
{
    const int g  = blockIdx.x & 7;
    const int lo = (int)(((long long)g * n) >> 3);
    const int hi = (int)(((long long)(g + 1) * n) >> 3);
    const int idx = (blockIdx.x >> 3) * 1024 + threadIdx.x * 4;
    if (idx + 3 < nE) {
        int4 r4 = *reinterpret_cast<const int4*>(rows + idx);
        int4 c4 = *reinterpret_cast<const int4*>(cols + idx);
        if (r4.x >= lo && r4.x < hi) colsorted[atomicAdd(&cur[r4.x], 1)] = c4.x;
        if (r4.y >= lo && r4.y < hi) colsorted[atomicAdd(&cur[r4.y], 1)] = c4.y;
        if (r4.z >= lo && r4.z < hi) colsorted[atomicAdd(&cur[r4.z], 1)] = c4.z;
        if (r4.w >= lo && r4.w < hi) colsorted[atomicAdd(&cur[r4.w], 1)] = c4.w;
    } else {
        for (int i = 0; i < 4; ++i)
            if (idx + i < nE) {
                int r = rows[idx + i];
                if (r >= lo && r < hi)
                    colsorted[atomicAdd(&cur[r], 1)] = cols[idx + i];
            }
    }
}

// ---- aggregation: one wave per row, 4 edges in flight (16 lanes each) ----
// q bf16 [n][128]; kv record [m][384]: k fp8 (128 B) then v bf16 (256 B)
__global__ __launch_bounds__(256) void agg_kernel(
    const unsigned short* __restrict__ q, const unsigned char* __restrict__ kv,
    const int* __restrict__ rowptr, const int* __restrict__ colsorted,
    float* __restrict__ out, int n)
{
    const int wave = (blockIdx.x * 256 + threadIdx.x) >> 6;
    if (wave >= n) return;
    const int lane = threadIdx.x & 63;
    const int sub  = lane >> 4;
    const int l    = lane & 15;

    const uint4 qa = *reinterpret_cast<const uint4*>(q + (size_t)wave * D + l * 8);
    float qf[8];
    qf[0] = bflo(qa.x); qf[1] = bfhi(qa.x);
    qf[2] = bflo(qa.y); qf[3] = bfhi(qa.y);
    qf[4] = bflo(qa.z); qf[5] = bfhi(qa.z);
    qf[6] = bflo(qa.w); qf[7] = bfhi(qa.w);

    float acc[8] = {0.f,0.f,0.f,0.f,0.f,0.f,0.f,0.f};
    const int start = rowptr[wave], end = rowptr[wave + 1];

    #pragma unroll 2
    for (int i = start + sub; i < end; i += 4) {
        const int c = colsorted[i];
        const unsigned char* rec = kv + (size_t)c * KVREC;
        const uint2 kb = *reinterpret_cast<const uint2*>(rec + l * 8);
        const uint4 vb = *reinterpret_cast<const uint4*>(rec + 128 + l * 16);

        float kf[8];
        fp8x4d(kb.x, kf); fp8x4d(kb.y, kf + 4);

        float dot = 0.0f;
        #pragma unroll
        for (int j = 0; j < 8; ++j) dot = fmaf(qf[j], kf[j], dot);
        dot += __shfl_xor(dot, 1);
        dot += __shfl_xor(dot, 2);
        dot += __shfl_xor(dot, 4);
        dot += __shfl_xor(dot, 8);
        const float coef = 1.0f / (1.0f + expf(-dot * 0.08838834764831845f));

        acc[0] = fmaf(coef, bflo(vb.x), acc[0]);
        acc[1] = fmaf(coef, bfhi(vb.x), acc[1]);
        acc[2] = fmaf(coef, bflo(vb.y), acc[2]);
        acc[3] = fmaf(coef, bfhi(vb.y), acc[3]);
        acc[4] = fmaf(coef, bflo(vb.z), acc[4]);
        acc[5] = fmaf(coef, bfhi(vb.z), acc[5]);
        acc[6] = fmaf(coef, bflo(vb.w), acc[6]);
        acc[7] = fmaf(coef, bfhi(vb.w), acc[7]);
    }

    #pragma unroll
    for (int j = 0; j < 8; ++j) {
        acc[j] += __shfl_xor(acc[j], 16);
        acc[j] += __shfl_xor(acc[j], 32);
    }

    if (sub == 0) {
        float* op = out + (size_t)wave * D + l * 8;
        float4 o0 = {acc[0], acc[1], acc[2], acc[3]};
        float4 o1 = {acc[4], acc[5], acc[6], acc[7]};
        *reinterpret_cast<float4*>(op)     = o0;
        *reinterpret_cast<float4*>(op + 4) = o1;
    }
}

extern "C" void kernel_launch(void* const* d_in, const int* in_sizes, int n_in,
                              void* d_out, int out_size, void* d_ws, size_t ws_size,
                              hipStream_t stream) {
    const float* query  = (const float*)d_in[0];
    const float* memory = (const float*)d_in[1];
    const float* Wq     = (const float*)d_in[2];
    const float* bq     = (const float*)d_in[3];
    const float* Wk     = (const float*)d_in[4];
    const float* bk     = (const float*)d_in[5];
    const float* Wv     = (const float*)d_in[6];
    const float* bv     = (const float*)d_in[7];
    const int*   erows  = (const int*)d_in[8];
    const int*   ecols  = (const int*)d_in[9];

    const int n  = in_sizes[0] / D;   // 100000
    const int m  = in_sizes[1] / D;   // 100000
    const int nE = in_sizes[8];       // 1600000

    char* base = (char*)d_ws;
    size_t off = 0;
    auto carve = [&](size_t bytes) -> char* {
        char* p = base + off;
        off = (off + bytes + 255) & ~(size_t)255;
        return p;
    };
    unsigned short* q   = (unsigned short*)carve((size_t)n * D * sizeof(unsigned short));
    unsigned char*  kv  = (unsigned char*) carve((size_t)m * KVREC);
    unsigned short* F   = (unsigned short*)carve(3 * 32 * 64 * 8 * sizeof(unsigned short));
    int*   rowptr    = (int*)carve((size_t)(n + 1) * sizeof(int));
    int*   cnt       = (int*)carve((size_t)(n + 1) * sizeof(int));
    int*   bsum      = (int*)carve(256 * sizeof(int));
    int*   boff      = (int*)carve(256 * sizeof(int));
    int*   colsorted = (int*)carve((size_t)nE * sizeof(int));
    float* out       = (float*)d_out;

    unsigned short* Fq = F;
    unsigned short* Fk = F + 16384;
    unsigned short* Fv = F + 32768;

    dim3 blk(256);
    const int nbScan  = (n + 1023) / 1024;            // <=256
    const int nbEdge8 = ((nE + 1023) / 1024) * 8;     // sliced edge kernels

    // W fragment pre-pack (one kernel, 3 matrices)
    prepack3_kernel<<<dim3(192), blk, 0, stream>>>(Wq, Wk, Wv, F);

    // CSR build
    hipMemsetAsync(cnt, 0, (size_t)(n + 1) * sizeof(int), stream);
    hist_kernel<<<dim3(nbEdge8), blk, 0, stream>>>(erows, cnt, nE, n);
    scan_bsum_kernel<<<dim3(nbScan), blk, 0, stream>>>(cnt, bsum, n);
    scan_boff_kernel<<<dim3(1), blk, 0, stream>>>(bsum, boff, nbScan, rowptr + n);
    scan_write_kernel<<<dim3(nbScan), blk, 0, stream>>>(cnt, boff, rowptr, n);
    // cur := rowptr[0..n-1] (reuse cnt), then scatter appends in-place
    hipMemcpyAsync(cnt, rowptr, (size_t)n * sizeof(int), hipMemcpyDeviceToDevice, stream);
    scatter_kernel<<<dim3(nbEdge8), blk, 0, stream>>>(erows, ecols, cnt, colsorted, nE, n);

    // projections: q (bf16); k (fp8) + v (bf16) fused kv records (memory read once)
    const int nb = (n + 127) / 128;
    const int mb = (m + 127) / 128;
    proj_q_kernel<<<dim3(nb), blk, 0, stream>>>(query, Fq, bq, q, n);
    proj_kv_kernel<<<dim3(mb), blk, 0, stream>>>(memory, Fk, bk, Fv, bv, kv, m);

    // aggregation: one wave per row, writes all outputs (no out memset needed)
    agg_kernel<<<dim3((n * 64 + 255) / 256), blk, 0, stream>>>(q, kv, rowptr, colsorted, out, n);
}

// Round 8
// 313.397 us; speedup vs baseline: 18.8321x; 1.0970x over previous
//
#include <hip/hip_runtime.h>
#include <hip/hip_bf16.h>
#include <math.h>

#ifndef __has_builtin
#define __has_builtin(x) 0
#endif
#if __has_builtin(__builtin_amdgcn_cvt_pk_fp8_f32) && __has_builtin(__builtin_amdgcn_cvt_pk_f32_fp8)
#define FP8_HW 1
#else
#include <hip/hip_fp8.h>
#endif

#define D 128
#define KVREC 384   // 128 B k (fp8 e4m3) + 256 B v (bf16)

typedef float f32x16 __attribute__((ext_vector_type(16)));
typedef float f32x2  __attribute__((ext_vector_type(2)));
typedef short bf16x8 __attribute__((ext_vector_type(8)));

// gelu tanh-approx, exact rewrite: 0.5x(1+tanh(u)) == x / (1 + e^{-2u})
__device__ __forceinline__ float gelu_fast(float x) {
    float u = 0.7978845608028654f * (x + 0.044715f * x * x * x);
    return x / (1.0f + __expf(-2.0f * u));
}

__device__ __forceinline__ unsigned short f2bf(float f) {
    union { float f; unsigned u; } x; x.f = f;
    unsigned r = x.u + 0x7fff + ((x.u >> 16) & 1);   // RNE
    return (unsigned short)(r >> 16);
}

__device__ __forceinline__ float bflo(unsigned u) { return __uint_as_float(u << 16); }
__device__ __forceinline__ float bfhi(unsigned u) { return __uint_as_float(u & 0xffff0000u); }

__device__ __forceinline__ unsigned char f2fp8(float x) {
#ifdef FP8_HW
    return (unsigned char)(__builtin_amdgcn_cvt_pk_fp8_f32(x, x, 0, false) & 0xFF);
#else
    __hip_fp8_e4m3 h(x); return (unsigned char)h.__x;
#endif
}

__device__ __forceinline__ void fp8x4d(unsigned u, float* f) {
#ifdef FP8_HW
    f32x2 lo = __builtin_amdgcn_cvt_pk_f32_fp8((int)u, false);
    f32x2 hi = __builtin_amdgcn_cvt_pk_f32_fp8((int)u, true);
    f[0] = lo[0]; f[1] = lo[1]; f[2] = hi[0]; f[3] = hi[1];
#else
    #pragma unroll
    for (int i = 0; i < 4; ++i) {
        __hip_fp8_e4m3 h; h.__x = (unsigned char)((u >> (8 * i)) & 0xFF);
        f[i] = (float)h;
    }
#endif
}

// ================= fused_pre: hist (blocks < nbE8) || prepack (last 192) =====

__global__ __launch_bounds__(256) void fused_pre_kernel(
    const int* __restrict__ rows, int* __restrict__ cnt, int nE, int n, int nbE8,
    const float* __restrict__ W0, const float* __restrict__ W1,
    const float* __restrict__ W2, unsigned short* __restrict__ F)
{
    const int bid = blockIdx.x;
    if (bid < nbE8) {
        // ---- hist: XCD-sliced (group g = bid&7 owns rows [g*n/8,(g+1)*n/8)) ----
        const int g  = bid & 7;
        const int lo = (int)(((long long)g * n) >> 3);
        const int hi = (int)(((long long)(g + 1) * n) >> 3);
        const int idx = (bid >> 3) * 1024 + threadIdx.x * 4;
        if (idx + 3 < nE) {
            int4 r4 = *reinterpret_cast<const int4*>(rows + idx);
            if (r4.x >= lo && r4.x < hi) atomicAdd(&cnt[r4.x], 1);
            if (r4.y >= lo && r4.y < hi) atomicAdd(&cnt[r4.y], 1);
            if (r4.z >= lo && r4.z < hi) atomicAdd(&cnt[r4.z], 1);
            if (r4.w >= lo && r4.w < hi) atomicAdd(&cnt[r4.w], 1);
        } else {
            for (int i = 0; i < 4; ++i)
                if (idx + i < nE) {
                    int r = rows[idx + i];
                    if (r >= lo && r < hi) atomicAdd(&cnt[r], 1);
                }
        }
    } else {
        // ---- prepack: 3 W[128][128] -> MFMA B-fragment order (bf16) ----
        int gidx = (bid - nbE8) * 256 + threadIdx.x;
        if (gidx >= 3 * 32 * 64 * 8) return;
        const int midx = gidx >> 14;
        const int idx  = gidx & 16383;
        const float* W = midx == 0 ? W0 : (midx == 1 ? W1 : W2);
        int j  = idx & 7;
        int l  = (idx >> 3) & 63;
        int kt = (idx >> 9) & 7;
        int ct = idx >> 12;
        int kk = kt * 16 + (l >> 5) * 8 + j;
        int c  = ct * 32 + (l & 31);
        F[gidx] = f2bf(W[kk * D + c]);
    }
}

// ================= scan: block sums, then write (with inline boff re-scan) ===

__global__ __launch_bounds__(256) void scan_bsum_kernel(
    const int* __restrict__ cnt, int* __restrict__ bsum, int n)
{
    __shared__ int s[256];
    const int t = threadIdx.x;
    const int base = blockIdx.x * 1024 + t * 4;
    int sum = 0;
    if (base + 3 < n) {
        int4 c4 = *reinterpret_cast<const int4*>(cnt + base);
        sum = c4.x + c4.y + c4.z + c4.w;
    } else {
        for (int i = 0; i < 4; ++i) if (base + i < n) sum += cnt[base + i];
    }
    s[t] = sum;
    __syncthreads();
    #pragma unroll
    for (int off = 128; off > 0; off >>= 1) {
        if (t < off) s[t] += s[t + off];
        __syncthreads();
    }
    if (t == 0) bsum[blockIdx.x] = s[0];
}

// Each block re-scans bsum[0..nb) in LDS (removes the 1-block boff dispatch),
// then writes rowptr AND cur (removes the d2d memcpy dispatch).
__global__ __launch_bounds__(256) void scan_write2_kernel(
    const int* __restrict__ cnt, const int* __restrict__ bsum, int nb,
    int* __restrict__ rowptr, int* __restrict__ cur, int n)
{
    __shared__ int s[256];
    const int t = threadIdx.x;

    // phase A: inclusive scan of block sums
    s[t] = (t < nb) ? bsum[t] : 0;
    __syncthreads();
    #pragma unroll
    for (int off = 1; off < 256; off <<= 1) {
        int v = (t >= off) ? s[t - off] : 0;
        __syncthreads();
        s[t] += v;
        __syncthreads();
    }
    const int boffv = (blockIdx.x > 0) ? s[blockIdx.x - 1] : 0;  // exclusive
    const int total = s[255];
    if (blockIdx.x == 0 && t == 0) rowptr[n] = total;
    __syncthreads();   // everyone has boffv; safe to reuse s

    // phase B: per-1024-chunk scan
    const int base = blockIdx.x * 1024 + t * 4;
    int c[4] = {0, 0, 0, 0};
    if (base + 3 < n) {
        int4 c4 = *reinterpret_cast<const int4*>(cnt + base);
        c[0] = c4.x; c[1] = c4.y; c[2] = c4.z; c[3] = c4.w;
    } else {
        for (int i = 0; i < 4; ++i) if (base + i < n) c[i] = cnt[base + i];
    }
    const int tsum = c[0] + c[1] + c[2] + c[3];
    s[t] = tsum;
    __syncthreads();
    #pragma unroll
    for (int off = 1; off < 256; off <<= 1) {
        int v = (t >= off) ? s[t - off] : 0;
        __syncthreads();
        s[t] += v;
        __syncthreads();
    }
    int run = boffv + s[t] - tsum;
    int w0 = run;
    int w1 = run + c[0];
    int w2 = w1 + c[1];
    int w3 = w2 + c[2];
    if (base + 3 < n) {
        int4 wv = make_int4(w0, w1, w2, w3);
        *reinterpret_cast<int4*>(rowptr + base) = wv;
        *reinterpret_cast<int4*>(cur + base)    = wv;
    } else {
        int w[4] = {w0, w1, w2, w3};
        for (int i = 0; i < 4; ++i)
            if (base + i < n) { rowptr[base + i] = w[i]; cur[base + i] = w[i]; }
    }
}

// ========== fused_mid: scatter || proj_q || proj_kv (block-range branch) =====

__device__ __forceinline__ void proj_stage(
    const float* __restrict__ X, int row0, int n,
    unsigned short (*sX)[136], int tid)
{
    #pragma unroll
    for (int p = 0; p < 16; ++p) {
        int flat = p * 256 + tid;
        int r = flat >> 5;
        int c = (flat & 31) * 4;
        int gr = row0 + r; if (gr >= n) gr = n - 1;
        float4 x4 = *reinterpret_cast<const float4*>(X + (size_t)gr * D + c);
        uint2 pk;
        pk.x = (unsigned)f2bf(x4.x) | ((unsigned)f2bf(x4.y) << 16);
        pk.y = (unsigned)f2bf(x4.z) | ((unsigned)f2bf(x4.w) << 16);
        *reinterpret_cast<uint2*>(&sX[r][c]) = pk;
    }
}

__global__ __launch_bounds__(256) void fused_mid_kernel(
    // scatter
    const int* __restrict__ rows, const int* __restrict__ cols,
    int* __restrict__ cur, int* __restrict__ colsorted, int nE, int nbE8,
    // proj
    const float* __restrict__ Xq, const float* __restrict__ Xm,
    const unsigned short* __restrict__ Fq, const float* __restrict__ bq,
    unsigned short* __restrict__ qout,
    const unsigned short* __restrict__ Fk, const float* __restrict__ bk,
    const unsigned short* __restrict__ Fv, const float* __restrict__ bv,
    unsigned char* __restrict__ kv,
    int n, int m, int nbQ)
{
    __shared__ __align__(16) unsigned short sX[128][136];
    const int bid = blockIdx.x;
    const int tid = threadIdx.x;

    if (bid < nbE8) {
        // ---- scatter (XCD-sliced row ranges; cur pre-initialized to rowptr) ----
        const int g  = bid & 7;
        const int lo = (int)(((long long)g * n) >> 3);
        const int hi = (int)(((long long)(g + 1) * n) >> 3);
        const int idx = (bid >> 3) * 1024 + tid * 4;
        if (idx + 3 < nE) {
            int4 r4 = *reinterpret_cast<const int4*>(rows + idx);
            int4 c4 = *reinterpret_cast<const int4*>(cols + idx);
            if (r4.x >= lo && r4.x < hi) colsorted[atomicAdd(&cur[r4.x], 1)] = c4.x;
            if (r4.y >= lo && r4.y < hi) colsorted[atomicAdd(&cur[r4.y], 1)] = c4.y;
            if (r4.z >= lo && r4.z < hi) colsorted[atomicAdd(&cur[r4.z], 1)] = c4.z;
            if (r4.w >= lo && r4.w < hi) colsorted[atomicAdd(&cur[r4.w], 1)] = c4.w;
        } else {
            for (int i = 0; i < 4; ++i)
                if (idx + i < nE) {
                    int r = rows[idx + i];
                    if (r >= lo && r < hi)
                        colsorted[atomicAdd(&cur[r], 1)] = cols[idx + i];
                }
        }
        return;
    }

    const int pb = bid - nbE8;
    const bool isQ = pb < nbQ;
    const int row0 = (isQ ? pb : pb - nbQ) * 128;
    const int nn   = isQ ? n : m;

    proj_stage(isQ ? Xq : Xm, row0, nn, sX, tid);
    __syncthreads();

    const int l = tid & 63;
    const int w = tid >> 6;
    const int arow = w * 32 + (l & 31);

    bf16x8 af[8];
    #pragma unroll
    for (int kt = 0; kt < 8; ++kt)
        af[kt] = *reinterpret_cast<const bf16x8*>(&sX[arow][kt * 16 + (l >> 5) * 8]);

    if (isQ) {
        #pragma unroll
        for (int ct = 0; ct < 4; ++ct) {
            f32x16 acc = {};
            #pragma unroll
            for (int kt = 0; kt < 8; ++kt) {
                bf16x8 bfr = *reinterpret_cast<const bf16x8*>(Fq + ((size_t)((ct * 8 + kt) * 64 + l) * 8));
                acc = __builtin_amdgcn_mfma_f32_32x32x16_bf16(af[kt], bfr, acc, 0, 0, 0);
            }
            const int col = ct * 32 + (l & 31);
            const float bb = bq[col];
            #pragma unroll
            for (int reg = 0; reg < 16; ++reg) {
                int r  = (reg & 3) + 8 * (reg >> 2) + 4 * (l >> 5);
                int gr = row0 + w * 32 + r;
                if (gr < nn)
                    qout[(size_t)gr * D + col] = f2bf(gelu_fast(acc[reg] + bb));
            }
        }
    } else {
        for (int mat = 0; mat < 2; ++mat) {
            const unsigned short* F = mat ? Fv : Fk;
            const float* bias       = mat ? bv : bk;
            #pragma unroll
            for (int ct = 0; ct < 4; ++ct) {
                f32x16 acc = {};
                #pragma unroll
                for (int kt = 0; kt < 8; ++kt) {
                    bf16x8 bfr = *reinterpret_cast<const bf16x8*>(F + ((size_t)((ct * 8 + kt) * 64 + l) * 8));
                    acc = __builtin_amdgcn_mfma_f32_32x32x16_bf16(af[kt], bfr, acc, 0, 0, 0);
                }
                const int col = ct * 32 + (l & 31);
                const float bb = bias[col];
                #pragma unroll
                for (int reg = 0; reg < 16; ++reg) {
                    int r  = (reg & 3) + 8 * (reg >> 2) + 4 * (l >> 5);
                    int gr = row0 + w * 32 + r;
                    if (gr < nn) {
                        unsigned char* rec = kv + (size_t)gr * KVREC;
                        float val = gelu_fast(acc[reg] + bb);
                        if (mat == 0)
                            rec[col] = f2fp8(val);
                        else
                            reinterpret_cast<unsigned short*>(rec + 128)[col] = f2bf(val);
                    }
                }
            }
        }
    }
}

// ---- aggregation: one wave per row, 4 edges in flight (16 lanes each) ----
// q bf16 [n][128]; kv record [m][384]: k fp8 (128 B) then v bf16 (256 B)
__global__ __launch_bounds__(256) void agg_kernel(
    const unsigned short* __restrict__ q, const unsigned char* __restrict__ kv,
    const int* __restrict__ rowptr, const int* __restrict__ colsorted,
    float* __restrict__ out, int n)
{
    const int wave = (blockIdx.x * 256 + threadIdx.x) >> 6;
    if (wave >= n) return;
    const int lane = threadIdx.x & 63;
    const int sub  = lane >> 4;
    const int l    = lane & 15;

    const uint4 qa = *reinterpret_cast<const uint4*>(q + (size_t)wave * D + l * 8);
    float qf[8];
    qf[0] = bflo(qa.x); qf[1] = bfhi(qa.x);
    qf[2] = bflo(qa.y); qf[3] = bfhi(qa.y);
    qf[4] = bflo(qa.z); qf[5] = bfhi(qa.z);
    qf[6] = bflo(qa.w); qf[7] = bfhi(qa.w);

    float acc[8] = {0.f,0.f,0.f,0.f,0.f,0.f,0.f,0.f};
    const int start = rowptr[wave], end = rowptr[wave + 1];

    #pragma unroll 2
    for (int i = start + sub; i < end; i += 4) {
        const int c = colsorted[i];
        const unsigned char* rec = kv + (size_t)c * KVREC;
        const uint2 kb = *reinterpret_cast<const uint2*>(rec + l * 8);
        const uint4 vb = *reinterpret_cast<const uint4*>(rec + 128 + l * 16);

        float kf[8];
        fp8x4d(kb.x, kf); fp8x4d(kb.y, kf + 4);

        float dot = 0.0f;
        #pragma unroll
        for (int j = 0; j < 8; ++j) dot = fmaf(qf[j], kf[j], dot);
        dot += __shfl_xor(dot, 1);
        dot += __shfl_xor(dot, 2);
        dot += __shfl_xor(dot, 4);
        dot += __shfl_xor(dot, 8);
        const float coef = 1.0f / (1.0f + __expf(-dot * 0.08838834764831845f));

        acc[0] = fmaf(coef, bflo(vb.x), acc[0]);
        acc[1] = fmaf(coef, bfhi(vb.x), acc[1]);
        acc[2] = fmaf(coef, bflo(vb.y), acc[2]);
        acc[3] = fmaf(coef, bfhi(vb.y), acc[3]);
        acc[4] = fmaf(coef, bflo(vb.z), acc[4]);
        acc[5] = fmaf(coef, bfhi(vb.z), acc[5]);
        acc[6] = fmaf(coef, bflo(vb.w), acc[6]);
        acc[7] = fmaf(coef, bfhi(vb.w), acc[7]);
    }

    #pragma unroll
    for (int j = 0; j < 8; ++j) {
        acc[j] += __shfl_xor(acc[j], 16);
        acc[j] += __shfl_xor(acc[j], 32);
    }

    if (sub == 0) {
        float* op = out + (size_t)wave * D + l * 8;
        float4 o0 = {acc[0], acc[1], acc[2], acc[3]};
        float4 o1 = {acc[4], acc[5], acc[6], acc[7]};
        *reinterpret_cast<float4*>(op)     = o0;
        *reinterpret_cast<float4*>(op + 4) = o1;
    }
}

extern "C" void kernel_launch(void* const* d_in, const int* in_sizes, int n_in,
                              void* d_out, int out_size, void* d_ws, size_t ws_size,
                              hipStream_t stream) {
    const float* query  = (const float*)d_in[0];
    const float* memory = (const float*)d_in[1];
    const float* Wq     = (const float*)d_in[2];
    const float* bq     = (const float*)d_in[3];
    const float* Wk     = (const float*)d_in[4];
    const float* bk     = (const float*)d_in[5];
    const float* Wv     = (const float*)d_in[6];
    const float* bv     = (const float*)d_in[7];
    const int*   erows  = (const int*)d_in[8];
    const int*   ecols  = (const int*)d_in[9];

    const int n  = in_sizes[0] / D;   // 100000
    const int m  = in_sizes[1] / D;   // 100000
    const int nE = in_sizes[8];       // 1600000

    char* base = (char*)d_ws;
    size_t off = 0;
    auto carve = [&](size_t bytes) -> char* {
        char* p = base + off;
        off = (off + bytes + 255) & ~(size_t)255;
        return p;
    };
    unsigned short* q   = (unsigned short*)carve((size_t)n * D * sizeof(unsigned short));
    unsigned char*  kv  = (unsigned char*) carve((size_t)m * KVREC);
    unsigned short* F   = (unsigned short*)carve(3 * 32 * 64 * 8 * sizeof(unsigned short));
    int*   rowptr    = (int*)carve((size_t)(n + 1) * sizeof(int));
    int*   cnt       = (int*)carve((size_t)(n + 1) * sizeof(int));
    int*   cur       = (int*)carve((size_t)(n + 1) * sizeof(int));
    int*   bsum      = (int*)carve(256 * sizeof(int));
    int*   colsorted = (int*)carve((size_t)nE * sizeof(int));
    float* out       = (float*)d_out;

    unsigned short* Fq = F;
    unsigned short* Fk = F + 16384;
    unsigned short* Fv = F + 32768;

    dim3 blk(256);
    const int nbScan = (n + 1023) / 1024;            // 98 <= 256
    const int nbE8   = ((nE + 1023) / 1024) * 8;     // sliced edge blocks
    const int nbQ    = (n + 127) / 128;
    const int nbM    = (m + 127) / 128;

    // 1) zero counters
    hipMemsetAsync(cnt, 0, (size_t)(n + 1) * sizeof(int), stream);
    // 2) hist || prepack
    fused_pre_kernel<<<dim3(nbE8 + 192), blk, 0, stream>>>(
        erows, cnt, nE, n, nbE8, Wq, Wk, Wv, F);
    // 3) block sums
    scan_bsum_kernel<<<dim3(nbScan), blk, 0, stream>>>(cnt, bsum, n);
    // 4) rowptr + cur (inline boff re-scan)
    scan_write2_kernel<<<dim3(nbScan), blk, 0, stream>>>(cnt, bsum, nbScan, rowptr, cur, n);
    // 5) scatter || proj_q || proj_kv
    fused_mid_kernel<<<dim3(nbE8 + nbQ + nbM), blk, 0, stream>>>(
        erows, ecols, cur, colsorted, nE, nbE8,
        query, memory, Fq, bq, q, Fk, bk, Fv, bv, kv, n, m, nbQ);
    // 6) aggregation (writes all outputs; no out memset needed)
    agg_kernel<<<dim3((n * 64 + 255) / 256), blk, 0, stream>>>(q, kv, rowptr, colsorted, out, n);
}